// Round 3
// baseline (556.758 us; speedup 1.0000x reference)
//
#include <hip/hip_runtime.h>
#include <hip/hip_bf16.h>

// Problem constants
#define BB 4
#define LL 2048
#define DD 1024
#define NN 16
#define BL (BB * LL)   // 8192 rows
#define NC 32          // scan chunks per sequence
#define LC 64          // chunk length (NC*LC == LL)

typedef float f32x4 __attribute__((ext_vector_type(4)));
typedef __bf16 bf16x8 __attribute__((ext_vector_type(8)));

__device__ __forceinline__ float fast_sigmoid(float x) {
  return 1.f / (1.f + __expf(-x));
}

// ---------------- fused weight prep ----------------
// z<4: transpose+cvt 1024x1024 f32 (K x N) -> N x K bf16 slabs
// z==4: pack W_B/W_C into wdtbc rows 1024..1055; zero rows 1056..1151
__global__ __launch_bounds__(256) void k_prep(const float* __restrict__ w1,
                                              const float* __restrict__ v1,
                                              const float* __restrict__ wdt,
                                              const float* __restrict__ w2,
                                              const float* __restrict__ WB,
                                              const float* __restrict__ WC,
                                              __hip_bfloat16* __restrict__ wcat,
                                              __hip_bfloat16* __restrict__ wdtbc,
                                              __hip_bfloat16* __restrict__ w2T) {
  const int z = blockIdx.z;
  if (z < 4) {
    const float* src = (z == 0) ? w1 : (z == 1) ? v1 : (z == 2) ? wdt : w2;
    __hip_bfloat16* dst = (z == 0) ? wcat
                        : (z == 1) ? (wcat + (size_t)1024 * DD)
                        : (z == 2) ? wdtbc : w2T;
    __shared__ float tile[32][33];
    const int kt = blockIdx.x * 32, nt = blockIdx.y * 32;
    const int tx = threadIdx.x & 31, ty = threadIdx.x >> 5;  // ty 0..7
#pragma unroll
    for (int j = 0; j < 32; j += 8)
      tile[ty + j][tx] = src[(size_t)(kt + ty + j) * DD + nt + tx];
    __syncthreads();
#pragma unroll
    for (int j = 0; j < 32; j += 8)
      dst[(size_t)(nt + ty + j) * DD + kt + tx] = __float2bfloat16(tile[tx][ty + j]);
  } else {
    const int id = blockIdx.y * 32 + blockIdx.x;  // 0..1023
    if (id < 128) {
      const int idx = id * 256 + threadIdx.x;  // 0..32767
      const int k = idx & 1023, n = idx >> 10;  // n in 0..31
      const float v = (n < 16) ? WB[(size_t)k * 16 + n] : WC[(size_t)k * 16 + (n - 16)];
      wdtbc[(size_t)(1024 + n) * DD + k] = __float2bfloat16(v);
    } else if (id < 512) {
      const int idx = (id - 128) * 256 + threadIdx.x;  // 0..98303 = 96*1024
      wdtbc[(size_t)1056 * DD + idx] = __float2bfloat16(0.f);
    }
  }
}

// ---------------- layernorm: f32 (BL x D) -> bf16 ----------------
__global__ __launch_bounds__(256) void k_layernorm(const float* __restrict__ x,
                                                   const float* __restrict__ g,
                                                   const float* __restrict__ b,
                                                   __hip_bfloat16* __restrict__ out) {
  const int row = blockIdx.x;
  const int tid = threadIdx.x;
  const f32x4 xv = *(const f32x4*)(x + (size_t)row * DD + tid * 4);
  float s = xv[0] + xv[1] + xv[2] + xv[3];
  float sq = xv[0] * xv[0] + xv[1] * xv[1] + xv[2] * xv[2] + xv[3] * xv[3];
#pragma unroll
  for (int o = 32; o > 0; o >>= 1) {
    s += __shfl_down(s, o);
    sq += __shfl_down(sq, o);
  }
  __shared__ float red[8];
  const int wave = tid >> 6, lane = tid & 63;
  if (lane == 0) { red[wave] = s; red[4 + wave] = sq; }
  __syncthreads();
  s = red[0] + red[1] + red[2] + red[3];
  sq = red[4] + red[5] + red[6] + red[7];
  const float mean = s * (1.f / DD);
  const float var = sq * (1.f / DD) - mean * mean;
  const float rs = rsqrtf(var + 1e-5f);
  const f32x4 gv = *(const f32x4*)(g + tid * 4);
  const f32x4 bv = *(const f32x4*)(b + tid * 4);
  union { ushort4 u; __hip_bfloat16 h[4]; } cv;
#pragma unroll
  for (int j = 0; j < 4; ++j)
    cv.h[j] = __float2bfloat16((xv[j] - mean) * rs * gv[j] + bv[j]);
  *reinterpret_cast<ushort4*>(&out[(size_t)row * DD + tid * 4]) = cv.u;
}

// ---------------- bf16 MFMA GEMM, 128x128 tile, LDS-FREE direct-to-register ----------------
// No barriers in the K-loop: fragments load straight from global (L1/L2 serve the
// reuse), software-pipelined one 32-wide k-tile deep in registers so the compiler
// emits partial vmcnt waits (AITER-style). Tail group over-reads <=48KB past the
// operand -- all operands sit inside d_ws with a following region, so no fault.
// A: M x 1024 bf16 row-major. W: N x 1024 bf16 row-major (pre-transposed).
// EPI 1: o0=x1(bf16,+bias0), o1=v(bf16, silu(+bias1))           [N=2048]
// EPI 2: o0=dt(bf16, softplus(+bias0)), o1=Bt(f32), o2=Ct(f32)  [N=1152]
// EPI 3: o0=out(f32, +bias0)                                    [N=1024]
template <int EPI>
__device__ __forceinline__ void gemm_body(const __hip_bfloat16* __restrict__ Ag,
                                          const __hip_bfloat16* __restrict__ Wg,
                                          void* __restrict__ o0, void* __restrict__ o1,
                                          void* __restrict__ o2,
                                          const float* __restrict__ bias0,
                                          const float* __restrict__ bias1) {
  const int tid = threadIdx.x;
  const int wave = tid >> 6, lane = tid & 63;
  const int quad = lane >> 4, l16 = lane & 15;
  const int wm = wave & 1, wn = wave >> 1;
  const int m0 = blockIdx.x * 128 + wm * 64;
  const int n0 = blockIdx.y * 128 + wn * 64;
  // lane's fragment base: row = base + l16, k = quad*8; frag i adds 16 rows
  const __hip_bfloat16* ap = Ag + (size_t)(m0 + l16) * 1024 + quad * 8;
  const __hip_bfloat16* bp = Wg + (size_t)(n0 + l16) * 1024 + quad * 8;
  constexpr size_t RS = (size_t)16 * 1024;  // 16-row fragment stride (elements)

  f32x4 acc[4][4] = {};
  bf16x8 a0[4], b0[4], a1[4], b1[4];

#pragma unroll
  for (int i = 0; i < 4; ++i) {
    a0[i] = *(const bf16x8*)(ap + i * RS);
    b0[i] = *(const bf16x8*)(bp + i * RS);
  }

  for (int kt = 0; kt < 16; ++kt) {
    const __hip_bfloat16* apk = ap + (2 * kt + 1) * 32;
    const __hip_bfloat16* bpk = bp + (2 * kt + 1) * 32;
#pragma unroll
    for (int i = 0; i < 4; ++i) {
      a1[i] = *(const bf16x8*)(apk + i * RS);
      b1[i] = *(const bf16x8*)(bpk + i * RS);
    }
#pragma unroll
    for (int i = 0; i < 4; ++i)
#pragma unroll
      for (int j = 0; j < 4; ++j)
        acc[i][j] = __builtin_amdgcn_mfma_f32_16x16x32_bf16(a0[i], b0[j], acc[i][j], 0, 0, 0);
    // k-tile 2kt+2 (at kt==15 this over-reads one tile past K; never consumed)
#pragma unroll
    for (int i = 0; i < 4; ++i) {
      a0[i] = *(const bf16x8*)(apk + 32 + i * RS);
      b0[i] = *(const bf16x8*)(bpk + 32 + i * RS);
    }
#pragma unroll
    for (int i = 0; i < 4; ++i)
#pragma unroll
      for (int j = 0; j < 4; ++j)
        acc[i][j] = __builtin_amdgcn_mfma_f32_16x16x32_bf16(a1[i], b1[j], acc[i][j], 0, 0, 0);
  }

  // epilogue: C/D layout col = lane&15, row = quad*4 + reg  [verified m89/m91]
  const int em0 = blockIdx.x * 128 + wm * 64 + quad * 4;
  const int en0 = blockIdx.y * 128 + wn * 64 + l16;
#pragma unroll
  for (int i = 0; i < 4; ++i) {
#pragma unroll
    for (int r = 0; r < 4; ++r) {
      const int m = em0 + i * 16 + r;
#pragma unroll
      for (int j = 0; j < 4; ++j) {
        const int n = en0 + j * 16;
        const float val = acc[i][j][r];
        if constexpr (EPI == 1) {
          if (n < 1024) {
            ((__hip_bfloat16*)o0)[(size_t)m * DD + n] = __float2bfloat16(val + bias0[n]);
          } else {
            const float t = val + bias1[n - 1024];
            ((__hip_bfloat16*)o1)[(size_t)m * DD + (n - 1024)] =
                __float2bfloat16(t * fast_sigmoid(t));
          }
        } else if constexpr (EPI == 2) {
          if (n < 1024) {
            const float t = val + bias0[n];
            const float sp = (t > 15.f) ? t : __logf(1.f + __expf(t));
            ((__hip_bfloat16*)o0)[(size_t)m * DD + n] = __float2bfloat16(sp);
          } else if (n < 1040) {
            ((float*)o1)[(size_t)m * NN + (n - 1024)] = val;
          } else if (n < 1056) {
            ((float*)o2)[(size_t)m * NN + (n - 1040)] = val;
          }
        } else {
          ((float*)o0)[(size_t)m * DD + n] = val + bias0[n];
        }
      }
    }
  }
}

__global__ __launch_bounds__(256) void k_gemm_xv(const __hip_bfloat16* __restrict__ Ag,
                                                 const __hip_bfloat16* __restrict__ Wg,
                                                 void* o0, void* o1,
                                                 const float* __restrict__ b0,
                                                 const float* __restrict__ b1) {
  gemm_body<1>(Ag, Wg, o0, o1, nullptr, b0, b1);
}
__global__ __launch_bounds__(256) void k_gemm_dbc(const __hip_bfloat16* __restrict__ Ag,
                                                  const __hip_bfloat16* __restrict__ Wg,
                                                  void* o0, void* o1, void* o2,
                                                  const float* __restrict__ b0) {
  gemm_body<2>(Ag, Wg, o0, o1, o2, b0, nullptr);
}
__global__ __launch_bounds__(256) void k_gemm_out(const __hip_bfloat16* __restrict__ Ag,
                                                  const __hip_bfloat16* __restrict__ Wg,
                                                  void* o0, const float* __restrict__ b0) {
  gemm_body<3>(Ag, Wg, o0, nullptr, nullptr, b0, nullptr);
}

// ---------------- depthwise conv3 (pad 1) + SiLU, bf16 -> bf16, x8 vectorized ----------------
__global__ __launch_bounds__(256) void k_conv_silu(const __hip_bfloat16* __restrict__ x1,
                                                   const float* __restrict__ w,
                                                   __hip_bfloat16* __restrict__ out) {
  const size_t e = ((size_t)blockIdx.x * 256 + threadIdx.x) * 8;  // elem idx over BL*D
  const int d = (int)(e & 1023);
  const int l = (int)((e >> 10) & 2047);
  const bf16x8 zero = {};
  const bf16x8 xm = (l > 0) ? *(const bf16x8*)(x1 + e - DD) : zero;
  const bf16x8 x0 = *(const bf16x8*)(x1 + e);
  const bf16x8 xp = (l < LL - 1) ? *(const bf16x8*)(x1 + e + DD) : zero;
  bf16x8 o;
#pragma unroll
  for (int j = 0; j < 8; ++j) {
    const float w0 = w[(d + j) * 3 + 0], w1 = w[(d + j) * 3 + 1], w2 = w[(d + j) * 3 + 2];
    const float a = w0 * (float)xm[j] + w1 * (float)x0[j] + w2 * (float)xp[j];
    o[j] = (__bf16)(a * fast_sigmoid(a));
  }
  *(bf16x8*)(out + e) = o;
}

// ---------------- selective scan, chunked (3 passes) ----------------
// pass 1: per (b, chunk, d): local scan from h=0 -> h_end; P = exp(A * sum(dt))
__global__ __launch_bounds__(256) void k_scan1(const __hip_bfloat16* __restrict__ dt,
                                               const __hip_bfloat16* __restrict__ u,
                                               const float* __restrict__ Bt,
                                               const float* __restrict__ A_log,
                                               float* __restrict__ P,
                                               float* __restrict__ hend) {
  const int d = blockIdx.x * 256 + threadIdx.x;
  const int c = blockIdx.y, b = blockIdx.z;
  __shared__ float Bsh[LC * NN];  // 4KB
  ((f32x4*)Bsh)[threadIdx.x] = ((const f32x4*)(Bt + (size_t)(b * LL + c * LC) * NN))[threadIdx.x];
  float a[NN];
#pragma unroll
  for (int n = 0; n < NN; ++n) a[n] = -__expf(A_log[(size_t)d * NN + n]);
  __syncthreads();
  float h[NN] = {};
  float sdt = 0.f;
  size_t idx = (size_t)(b * LL + c * LC) * DD + d;
#pragma unroll 4
  for (int t = 0; t < LC; ++t, idx += DD) {
    const float dtv = __bfloat162float(dt[idx]);
    const float uv = __bfloat162float(u[idx]);
    sdt += dtv;
    const float du = dtv * uv;
#pragma unroll
    for (int n = 0; n < NN; ++n)
      h[n] = __expf(dtv * a[n]) * h[n] + du * Bsh[t * NN + n];
  }
  const size_t o = ((size_t)((b * NC + c) * DD + d)) * NN;
#pragma unroll
  for (int n = 0; n < NN; ++n) {
    P[o + n] = __expf(sdt * a[n]);
    hend[o + n] = h[n];
  }
}

// pass 2: tiny inter-chunk scan per (b,d,n); converts hend -> hstart in place
__global__ __launch_bounds__(256) void k_scan2(const float* __restrict__ P, float* __restrict__ h) {
  const int gidx = blockIdx.x * 256 + threadIdx.x;  // BB*DD*NN = 65536
  const int n = gidx & 15, d = (gidx >> 4) & 1023, b = gidx >> 14;
  float hs = 0.f;
  size_t off = ((size_t)b * NC * DD + d) * NN + n;
  const size_t stride = (size_t)DD * NN;
  for (int c = 0; c < NC; ++c, off += stride) {
    const float he = h[off];
    const float p = P[off];
    h[off] = hs;  // now h_start for chunk c
    hs = p * hs + he;
  }
}

// pass 3: re-scan with correct h_start, compute y, fuse D_skip and *v, emit bf16 A for GEMM3
__global__ __launch_bounds__(256) void k_scan3(const __hip_bfloat16* __restrict__ dt,
                                               const __hip_bfloat16* __restrict__ u,
                                               const float* __restrict__ Bt,
                                               const float* __restrict__ Ct,
                                               const float* __restrict__ A_log,
                                               const float* __restrict__ hstart,
                                               const float* __restrict__ Dskip,
                                               const __hip_bfloat16* __restrict__ v,
                                               __hip_bfloat16* __restrict__ yA) {
  const int d = blockIdx.x * 256 + threadIdx.x;
  const int c = blockIdx.y, b = blockIdx.z;
  __shared__ float Bsh[LC * NN];
  __shared__ float Csh[LC * NN];
  ((f32x4*)Bsh)[threadIdx.x] = ((const f32x4*)(Bt + (size_t)(b * LL + c * LC) * NN))[threadIdx.x];
  ((f32x4*)Csh)[threadIdx.x] = ((const f32x4*)(Ct + (size_t)(b * LL + c * LC) * NN))[threadIdx.x];
  float a[NN];
#pragma unroll
  for (int n = 0; n < NN; ++n) a[n] = -__expf(A_log[(size_t)d * NN + n]);
  const float dsk = Dskip[d];
  float h[NN];
  const size_t o = ((size_t)((b * NC + c) * DD + d)) * NN;
#pragma unroll
  for (int n = 0; n < NN; ++n) h[n] = hstart[o + n];
  __syncthreads();
  size_t idx = (size_t)(b * LL + c * LC) * DD + d;
#pragma unroll 2
  for (int t = 0; t < LC; ++t, idx += DD) {
    const float dtv = __bfloat162float(dt[idx]);
    const float uv = __bfloat162float(u[idx]);
    const float du = dtv * uv;
    float y = 0.f;
#pragma unroll
    for (int n = 0; n < NN; ++n) {
      h[n] = __expf(dtv * a[n]) * h[n] + du * Bsh[t * NN + n];
      y += h[n] * Csh[t * NN + n];
    }
    const float xssm = y + uv * dsk;
    const float vv = __bfloat162float(v[idx]);
    yA[idx] = __float2bfloat16(xssm * vv);
  }
}

// ---------------- host launcher ----------------
extern "C" void kernel_launch(void* const* d_in, const int* in_sizes, int n_in,
                              void* d_out, int out_size, void* d_ws, size_t ws_size,
                              hipStream_t stream) {
  const float* x      = (const float*)d_in[0];
  const float* ln_g   = (const float*)d_in[1];
  const float* ln_b   = (const float*)d_in[2];
  const float* w1_w   = (const float*)d_in[3];
  const float* w1_b   = (const float*)d_in[4];
  const float* v1_w   = (const float*)d_in[5];
  const float* v1_b   = (const float*)d_in[6];
  const float* w2_w   = (const float*)d_in[7];
  const float* w2_b   = (const float*)d_in[8];
  const float* conv_w = (const float*)d_in[9];
  const float* A_log  = (const float*)d_in[10];
  const float* D_skip = (const float*)d_in[11];
  const float* W_dt   = (const float*)d_in[12];
  const float* b_dt   = (const float*)d_in[13];
  const float* W_B    = (const float*)d_in[14];
  const float* W_C    = (const float*)d_in[15];

  char* ws = (char*)d_ws;
  // byte offsets (lifetime-overlapped), total ~93.6 MB; every GEMM operand has a
  // following region so the K-loop tail over-read stays in-bounds.
  const size_t OFF_SLOTA = 0;             // xnorm bf16 -> later xconv bf16   (16 MB)
  const size_t OFF_SLOTB = 16777216;      // x1 bf16   -> later dt bf16       (16 MB)
  const size_t OFF_VBUF  = 33554432;      // v bf16                           (16 MB)
  const size_t OFF_YA    = 50331648;      // (x_ssm*v) bf16                   (16 MB)
  const size_t OFF_WCAT  = 67108864;      // [w1;v1]^T bf16 2048x1024          (4 MB)
  const size_t OFF_WDTBC = 71303168;      // [W_dt;W_B;W_C;pad]^T 1152x1024  (2.25 MB)
  const size_t OFF_W2T   = 73662464;      // w2^T bf16 1024x1024               (2 MB)
  const size_t OFF_BT    = 75759616;      // Bt f32 8192x16                  (0.5 MB)
  const size_t OFF_CT    = 76283904;      // Ct f32 8192x16                  (0.5 MB)
  const size_t OFF_P     = 76808192;      // chunk decay products              (8 MB)
  const size_t OFF_H     = 85196800;      // chunk h_end -> h_start            (8 MB)

  __hip_bfloat16* xnorm = (__hip_bfloat16*)(ws + OFF_SLOTA);
  __hip_bfloat16* xconv = (__hip_bfloat16*)(ws + OFF_SLOTA);
  __hip_bfloat16* x1    = (__hip_bfloat16*)(ws + OFF_SLOTB);
  __hip_bfloat16* dtb   = (__hip_bfloat16*)(ws + OFF_SLOTB);
  __hip_bfloat16* vbuf  = (__hip_bfloat16*)(ws + OFF_VBUF);
  __hip_bfloat16* yA    = (__hip_bfloat16*)(ws + OFF_YA);
  __hip_bfloat16* wcat  = (__hip_bfloat16*)(ws + OFF_WCAT);
  __hip_bfloat16* wdtbc = (__hip_bfloat16*)(ws + OFF_WDTBC);
  __hip_bfloat16* w2T   = (__hip_bfloat16*)(ws + OFF_W2T);
  float* Btf = (float*)(ws + OFF_BT);
  float* Ctf = (float*)(ws + OFF_CT);
  float* P   = (float*)(ws + OFF_P);
  float* H   = (float*)(ws + OFF_H);

  k_prep<<<dim3(32, 32, 5), 256, 0, stream>>>(w1_w, v1_w, W_dt, w2_w, W_B, W_C,
                                              wcat, wdtbc, w2T);

  k_layernorm<<<BL, 256, 0, stream>>>(x, ln_g, ln_b, xnorm);

  k_gemm_xv<<<dim3(BL / 128, 2048 / 128), 256, 0, stream>>>(
      xnorm, wcat, (void*)x1, (void*)vbuf, w1_b, v1_b);

  k_conv_silu<<<(BL * DD / 8) / 256, 256, 0, stream>>>(x1, conv_w, xconv);

  k_gemm_dbc<<<dim3(BL / 128, 1152 / 128), 256, 0, stream>>>(
      xconv, wdtbc, (void*)dtb, (void*)Btf, (void*)Ctf, b_dt);

  k_scan1<<<dim3(DD / 256, NC, BB), 256, 0, stream>>>(dtb, xconv, Btf, A_log, P, H);
  k_scan2<<<(BB * DD * NN) / 256, 256, 0, stream>>>(P, H);
  k_scan3<<<dim3(DD / 256, NC, BB), 256, 0, stream>>>(dtb, xconv, Btf, Ctf, A_log, H, D_skip,
                                                      vbuf, yA);

  k_gemm_out<<<dim3(BL / 128, 1024 / 128), 256, 0, stream>>>(yA, w2T, d_out, w2_b);
}

// Round 4
// 499.305 us; speedup vs baseline: 1.1151x; 1.1151x over previous
//
#include <hip/hip_runtime.h>
#include <hip/hip_bf16.h>

// Problem constants
#define BB 4
#define LL 2048
#define DD 1024
#define NN 16
#define BL (BB * LL)   // 8192 rows
#define NC 32          // scan chunks per sequence
#define LC 64          // chunk length (NC*LC == LL)
#define MB 1048576

typedef float f32x4 __attribute__((ext_vector_type(4)));
typedef __bf16 bf16x8 __attribute__((ext_vector_type(8)));

typedef __attribute__((address_space(1))) unsigned int as1_u32;
typedef __attribute__((address_space(3))) unsigned int as3_u32;

__device__ __forceinline__ void gl_lds16(const void* g, void* l) {
  // async global->LDS, 16B per lane, dest = uniform base + lane*16
  __builtin_amdgcn_global_load_lds((as1_u32*)g, (as3_u32*)l, 16, 0, 0);
}

__device__ __forceinline__ float fast_sigmoid(float x) {
  return 1.f / (1.f + __expf(-x));
}

// ---------------- fused weight prep + layernorm (one dispatch) ----------------
// z<4 : transpose+cvt 1024x1024 f32 (K x N) -> N x K bf16 slabs
// z==4: pack W_B/W_C into wdtbc rows 1024..1055; zero rows 1056..1279
// z>=5: layernorm row (z-5)*1024 + by*32 + bx  (8 z-slices = 8192 rows)
__global__ __launch_bounds__(256) void k_prep_ln(const float* __restrict__ w1,
                                                 const float* __restrict__ v1,
                                                 const float* __restrict__ wdt,
                                                 const float* __restrict__ w2,
                                                 const float* __restrict__ WB,
                                                 const float* __restrict__ WC,
                                                 __hip_bfloat16* __restrict__ wcat,
                                                 __hip_bfloat16* __restrict__ wdtbc,
                                                 __hip_bfloat16* __restrict__ w2T,
                                                 const float* __restrict__ x,
                                                 const float* __restrict__ ln_g,
                                                 const float* __restrict__ ln_b,
                                                 __hip_bfloat16* __restrict__ xnorm) {
  const int z = blockIdx.z;
  __shared__ float tile[32][33];
  __shared__ float red[8];
  if (z < 4) {
    const float* src = (z == 0) ? w1 : (z == 1) ? v1 : (z == 2) ? wdt : w2;
    __hip_bfloat16* dst = (z == 0) ? wcat
                        : (z == 1) ? (wcat + (size_t)1024 * DD)
                        : (z == 2) ? wdtbc : w2T;
    const int kt = blockIdx.x * 32, nt = blockIdx.y * 32;
    const int tx = threadIdx.x & 31, ty = threadIdx.x >> 5;  // ty 0..7
#pragma unroll
    for (int j = 0; j < 32; j += 8)
      tile[ty + j][tx] = src[(size_t)(kt + ty + j) * DD + nt + tx];
    __syncthreads();
#pragma unroll
    for (int j = 0; j < 32; j += 8)
      dst[(size_t)(nt + ty + j) * DD + kt + tx] = __float2bfloat16(tile[tx][ty + j]);
  } else if (z == 4) {
    const int id = blockIdx.y * 32 + blockIdx.x;  // 0..1023
    if (id < 128) {
      const int idx = id * 256 + threadIdx.x;  // 0..32767
      const int k = idx & 1023, n = idx >> 10;  // n in 0..31
      const float v = (n < 16) ? WB[(size_t)k * 16 + n] : WC[(size_t)k * 16 + (n - 16)];
      wdtbc[(size_t)(1024 + n) * DD + k] = __float2bfloat16(v);
    } else {
      const int idx = (id - 128) * 256 + threadIdx.x;  // 0..229375 = 224*1024
      wdtbc[(size_t)1056 * DD + idx] = __float2bfloat16(0.f);
    }
  } else {
    const int row = (z - 5) * 1024 + blockIdx.y * 32 + blockIdx.x;
    const int tid = threadIdx.x;
    const f32x4 xv = *(const f32x4*)(x + (size_t)row * DD + tid * 4);
    float s = xv[0] + xv[1] + xv[2] + xv[3];
    float sq = xv[0] * xv[0] + xv[1] * xv[1] + xv[2] * xv[2] + xv[3] * xv[3];
#pragma unroll
    for (int o = 32; o > 0; o >>= 1) {
      s += __shfl_down(s, o);
      sq += __shfl_down(sq, o);
    }
    const int wave = tid >> 6, lane = tid & 63;
    if (lane == 0) { red[wave] = s; red[4 + wave] = sq; }
    __syncthreads();
    s = red[0] + red[1] + red[2] + red[3];
    sq = red[4] + red[5] + red[6] + red[7];
    const float mean = s * (1.f / DD);
    const float var = sq * (1.f / DD) - mean * mean;
    const float rs = rsqrtf(var + 1e-5f);
    const f32x4 gv = *(const f32x4*)(ln_g + tid * 4);
    const f32x4 bv = *(const f32x4*)(ln_b + tid * 4);
    union { ushort4 u; __hip_bfloat16 h[4]; } cv;
#pragma unroll
    for (int j = 0; j < 4; ++j)
      cv.h[j] = __float2bfloat16((xv[j] - mean) * rs * gv[j] + bv[j]);
    *reinterpret_cast<ushort4*>(&xnorm[(size_t)row * DD + tid * 4]) = cv.u;
  }
}

// ---------------- bf16 MFMA GEMM, 128M x 256N tile, BK=32, 4 waves ----------------
// m97-style single-buffer LDS staging (global_load_lds width=16), but 2x wider
// N-tile: stages 24KB/iter for 128 MFMA-instr -> 2.1x arithmetic intensity per
// staged byte vs 128x128. Wave-tile 64x128 (acc[4][8], 128 AGPRs).
// A: M x 1024 bf16 row-major. W: N x 1024 bf16 row-major (pre-transposed).
// EPI 1: o0=x1(bf16,+bias0), o1=v(bf16, silu(+bias1))           [N=2048]
// EPI 2: o0=dt(bf16, softplus(+bias0)), o1=Bt(f32), o2=Ct(f32)  [N=1280 padded]
// EPI 3: o0=out(f32, +bias0)                                    [N=1024]
template <int EPI>
__device__ __forceinline__ void gemm_body(const __hip_bfloat16* __restrict__ Ag,
                                          const __hip_bfloat16* __restrict__ Wg,
                                          void* __restrict__ o0, void* __restrict__ o1,
                                          void* __restrict__ o2,
                                          const float* __restrict__ bias0,
                                          const float* __restrict__ bias1) {
  __shared__ unsigned short As[128 * 32];  // 8 KB
  __shared__ unsigned short Bs[256 * 32];  // 16 KB
  const int tid = threadIdx.x;
  const int wave = tid >> 6, lane = tid & 63;
  const int quad = lane >> 4, l16 = lane & 15;
  const int wm = wave & 1, wn = wave >> 1;

  // staging: each wave stages 32 rows of A (2 issues) and 64 rows of W (4 issues)
  const int srowA = wave * 32 + (lane >> 2);
  const int srowB = wave * 64 + (lane >> 2);
  const int sbyte = (lane & 3) * 16;
  const char* gA = (const char*)(Ag + (size_t)(blockIdx.x * 128 + srowA) * 1024) + sbyte;
  const char* gB = (const char*)(Wg + (size_t)(blockIdx.y * 256 + srowB) * 1024) + sbyte;
  char* lA = (char*)As + wave * 2048;
  char* lB = (char*)Bs + wave * 4096;

  f32x4 acc[4][8] = {};

  for (int kt = 0; kt < 32; ++kt) {
    gl_lds16(gA, lA);
    gl_lds16(gA + 16 * 2048, lA + 1024);
    gl_lds16(gB, lB);
    gl_lds16(gB + 16 * 2048, lB + 1024);
    gl_lds16(gB + 32 * 2048, lB + 2048);
    gl_lds16(gB + 48 * 2048, lB + 3072);
    gA += 64;
    gB += 64;
    __syncthreads();  // drains vmcnt -> LDS tiles ready
    bf16x8 af[4], bfr[8];
#pragma unroll
    for (int i = 0; i < 4; ++i)
      af[i] = *(const bf16x8*)(As + (wm * 64 + i * 16 + l16) * 32 + quad * 8);
#pragma unroll
    for (int j = 0; j < 8; ++j)
      bfr[j] = *(const bf16x8*)(Bs + (wn * 128 + j * 16 + l16) * 32 + quad * 8);
#pragma unroll
    for (int i = 0; i < 4; ++i)
#pragma unroll
      for (int j = 0; j < 8; ++j)
        acc[i][j] = __builtin_amdgcn_mfma_f32_16x16x32_bf16(af[i], bfr[j], acc[i][j], 0, 0, 0);
    __syncthreads();  // everyone done reading before next stage overwrites
  }

  // epilogue: C/D layout col = lane&15, row = quad*4 + reg  [verified m89/m91]
  const int em0 = blockIdx.x * 128 + wm * 64 + quad * 4;
  const int en0 = blockIdx.y * 256 + wn * 128 + l16;
#pragma unroll
  for (int i = 0; i < 4; ++i) {
#pragma unroll
    for (int r = 0; r < 4; ++r) {
      const int m = em0 + i * 16 + r;
#pragma unroll
      for (int j = 0; j < 8; ++j) {
        const int n = en0 + j * 16;
        const float val = acc[i][j][r];
        if constexpr (EPI == 1) {
          if (n < 1024) {
            ((__hip_bfloat16*)o0)[(size_t)m * DD + n] = __float2bfloat16(val + bias0[n]);
          } else {
            const float t = val + bias1[n - 1024];
            ((__hip_bfloat16*)o1)[(size_t)m * DD + (n - 1024)] =
                __float2bfloat16(t * fast_sigmoid(t));
          }
        } else if constexpr (EPI == 2) {
          if (n < 1024) {
            const float t = val + bias0[n];
            const float sp = (t > 15.f) ? t : __logf(1.f + __expf(t));
            ((__hip_bfloat16*)o0)[(size_t)m * DD + n] = __float2bfloat16(sp);
          } else if (n < 1040) {
            ((float*)o1)[(size_t)m * NN + (n - 1024)] = val;
          } else if (n < 1056) {
            ((float*)o2)[(size_t)m * NN + (n - 1040)] = val;
          }  // n >= 1056: padding, discard
        } else {
          ((float*)o0)[(size_t)m * DD + n] = val + bias0[n];
        }
      }
    }
  }
}

__global__ __launch_bounds__(256) void k_gemm_xv(const __hip_bfloat16* __restrict__ Ag,
                                                 const __hip_bfloat16* __restrict__ Wg,
                                                 void* o0, void* o1,
                                                 const float* __restrict__ b0,
                                                 const float* __restrict__ b1) {
  gemm_body<1>(Ag, Wg, o0, o1, nullptr, b0, b1);
}
__global__ __launch_bounds__(256) void k_gemm_dbc(const __hip_bfloat16* __restrict__ Ag,
                                                  const __hip_bfloat16* __restrict__ Wg,
                                                  void* o0, void* o1, void* o2,
                                                  const float* __restrict__ b0) {
  gemm_body<2>(Ag, Wg, o0, o1, o2, b0, nullptr);
}
__global__ __launch_bounds__(256) void k_gemm_out(const __hip_bfloat16* __restrict__ Ag,
                                                  const __hip_bfloat16* __restrict__ Wg,
                                                  void* o0, const float* __restrict__ b0) {
  gemm_body<3>(Ag, Wg, o0, nullptr, nullptr, b0, nullptr);
}

// ---------------- depthwise conv3 (pad 1) + SiLU, bf16 -> bf16, x8 vectorized ----------------
__global__ __launch_bounds__(256) void k_conv_silu(const __hip_bfloat16* __restrict__ x1,
                                                   const float* __restrict__ w,
                                                   __hip_bfloat16* __restrict__ out) {
  const size_t e = ((size_t)blockIdx.x * 256 + threadIdx.x) * 8;  // elem idx over BL*D
  const int d = (int)(e & 1023);
  const int l = (int)((e >> 10) & 2047);
  const bf16x8 zero = {};
  const bf16x8 xm = (l > 0) ? *(const bf16x8*)(x1 + e - DD) : zero;
  const bf16x8 x0 = *(const bf16x8*)(x1 + e);
  const bf16x8 xp = (l < LL - 1) ? *(const bf16x8*)(x1 + e + DD) : zero;
  bf16x8 o;
#pragma unroll
  for (int j = 0; j < 8; ++j) {
    const float w0 = w[(d + j) * 3 + 0], w1 = w[(d + j) * 3 + 1], w2 = w[(d + j) * 3 + 2];
    const float a = w0 * (float)xm[j] + w1 * (float)x0[j] + w2 * (float)xp[j];
    o[j] = (__bf16)(a * fast_sigmoid(a));
  }
  *(bf16x8*)(out + e) = o;
}

// ---------------- selective scan, chunked (3 passes) ----------------
// pass 1: per (b, chunk, d): local scan from h=0 -> h_end; P = exp(A * sum(dt))
__global__ __launch_bounds__(256) void k_scan1(const __hip_bfloat16* __restrict__ dt,
                                               const __hip_bfloat16* __restrict__ u,
                                               const float* __restrict__ Bt,
                                               const float* __restrict__ A_log,
                                               float* __restrict__ P,
                                               float* __restrict__ hend) {
  const int d = blockIdx.x * 256 + threadIdx.x;
  const int c = blockIdx.y, b = blockIdx.z;
  __shared__ float Bsh[LC * NN];  // 4KB
  ((f32x4*)Bsh)[threadIdx.x] = ((const f32x4*)(Bt + (size_t)(b * LL + c * LC) * NN))[threadIdx.x];
  float a[NN];
#pragma unroll
  for (int n = 0; n < NN; ++n) a[n] = -__expf(A_log[(size_t)d * NN + n]);
  __syncthreads();
  float h[NN] = {};
  float sdt = 0.f;
  size_t idx = (size_t)(b * LL + c * LC) * DD + d;
#pragma unroll 4
  for (int t = 0; t < LC; ++t, idx += DD) {
    const float dtv = __bfloat162float(dt[idx]);
    const float uv = __bfloat162float(u[idx]);
    sdt += dtv;
    const float du = dtv * uv;
#pragma unroll
    for (int n = 0; n < NN; ++n)
      h[n] = __expf(dtv * a[n]) * h[n] + du * Bsh[t * NN + n];
  }
  const size_t o = ((size_t)((b * NC + c) * DD + d)) * NN;
#pragma unroll
  for (int n = 0; n < NN; ++n) {
    P[o + n] = __expf(sdt * a[n]);
    hend[o + n] = h[n];
  }
}

// pass 2: tiny inter-chunk scan per (b,d,n); converts hend -> hstart in place
__global__ __launch_bounds__(256) void k_scan2(const float* __restrict__ P, float* __restrict__ h) {
  const int gidx = blockIdx.x * 256 + threadIdx.x;  // BB*DD*NN = 65536
  const int n = gidx & 15, d = (gidx >> 4) & 1023, b = gidx >> 14;
  float hs = 0.f;
  size_t off = ((size_t)b * NC * DD + d) * NN + n;
  const size_t stride = (size_t)DD * NN;
  for (int c = 0; c < NC; ++c, off += stride) {
    const float he = h[off];
    const float p = P[off];
    h[off] = hs;  // now h_start for chunk c
    hs = p * hs + he;
  }
}

// pass 3: re-scan with correct h_start, compute y, fuse D_skip and *v, emit bf16 A for GEMM3
__global__ __launch_bounds__(256) void k_scan3(const __hip_bfloat16* __restrict__ dt,
                                               const __hip_bfloat16* __restrict__ u,
                                               const float* __restrict__ Bt,
                                               const float* __restrict__ Ct,
                                               const float* __restrict__ A_log,
                                               const float* __restrict__ hstart,
                                               const float* __restrict__ Dskip,
                                               const __hip_bfloat16* __restrict__ v,
                                               __hip_bfloat16* __restrict__ yA) {
  const int d = blockIdx.x * 256 + threadIdx.x;
  const int c = blockIdx.y, b = blockIdx.z;
  __shared__ float Bsh[LC * NN];
  __shared__ float Csh[LC * NN];
  ((f32x4*)Bsh)[threadIdx.x] = ((const f32x4*)(Bt + (size_t)(b * LL + c * LC) * NN))[threadIdx.x];
  ((f32x4*)Csh)[threadIdx.x] = ((const f32x4*)(Ct + (size_t)(b * LL + c * LC) * NN))[threadIdx.x];
  float a[NN];
#pragma unroll
  for (int n = 0; n < NN; ++n) a[n] = -__expf(A_log[(size_t)d * NN + n]);
  const float dsk = Dskip[d];
  float h[NN];
  const size_t o = ((size_t)((b * NC + c) * DD + d)) * NN;
#pragma unroll
  for (int n = 0; n < NN; ++n) h[n] = hstart[o + n];
  __syncthreads();
  size_t idx = (size_t)(b * LL + c * LC) * DD + d;
#pragma unroll 2
  for (int t = 0; t < LC; ++t, idx += DD) {
    const float dtv = __bfloat162float(dt[idx]);
    const float uv = __bfloat162float(u[idx]);
    const float du = dtv * uv;
    float y = 0.f;
#pragma unroll
    for (int n = 0; n < NN; ++n) {
      h[n] = __expf(dtv * a[n]) * h[n] + du * Bsh[t * NN + n];
      y += h[n] * Csh[t * NN + n];
    }
    const float xssm = y + uv * dsk;
    const float vv = __bfloat162float(v[idx]);
    yA[idx] = __float2bfloat16(xssm * vv);
  }
}

// ---------------- host launcher ----------------
extern "C" void kernel_launch(void* const* d_in, const int* in_sizes, int n_in,
                              void* d_out, int out_size, void* d_ws, size_t ws_size,
                              hipStream_t stream) {
  const float* x      = (const float*)d_in[0];
  const float* ln_g   = (const float*)d_in[1];
  const float* ln_b   = (const float*)d_in[2];
  const float* w1_w   = (const float*)d_in[3];
  const float* w1_b   = (const float*)d_in[4];
  const float* v1_w   = (const float*)d_in[5];
  const float* v1_b   = (const float*)d_in[6];
  const float* w2_w   = (const float*)d_in[7];
  const float* w2_b   = (const float*)d_in[8];
  const float* conv_w = (const float*)d_in[9];
  const float* A_log  = (const float*)d_in[10];
  const float* D_skip = (const float*)d_in[11];
  const float* W_dt   = (const float*)d_in[12];
  const float* b_dt   = (const float*)d_in[13];
  const float* W_B    = (const float*)d_in[14];
  const float* W_C    = (const float*)d_in[15];

  char* ws = (char*)d_ws;
  // byte offsets (lifetime-overlapped), total ~89.5 MB
  const size_t OFF_SLOTA = 0;                    // xnorm -> later xconv (16 MB)
  const size_t OFF_SLOTB = (size_t)16 * MB;      // x1 -> later dt       (16 MB)
  const size_t OFF_VBUF  = (size_t)32 * MB;      // v bf16               (16 MB)
  const size_t OFF_YA    = (size_t)48 * MB;      // (x_ssm*v) bf16       (16 MB)
  const size_t OFF_WCAT  = (size_t)64 * MB;      // [w1;v1]^T 2048x1024   (4 MB)
  const size_t OFF_WDTBC = (size_t)68 * MB;      // [W_dt;B;C;pad]^T 1280x1024 (2.5 MB)
  const size_t OFF_W2T   = OFF_WDTBC + 2621440;  // w2^T 1024x1024        (2 MB)
  const size_t OFF_BT    = OFF_W2T + 2097152;    // Bt f32 8192x16      (0.5 MB)
  const size_t OFF_CT    = OFF_BT + 524288;      // Ct f32 8192x16      (0.5 MB)
  const size_t OFF_P     = OFF_CT + 524288;      // chunk decay products  (8 MB)
  const size_t OFF_H     = OFF_P + 8388608;      // chunk h_end->h_start  (8 MB)

  __hip_bfloat16* xnorm = (__hip_bfloat16*)(ws + OFF_SLOTA);
  __hip_bfloat16* xconv = (__hip_bfloat16*)(ws + OFF_SLOTA);
  __hip_bfloat16* x1    = (__hip_bfloat16*)(ws + OFF_SLOTB);
  __hip_bfloat16* dtb   = (__hip_bfloat16*)(ws + OFF_SLOTB);
  __hip_bfloat16* vbuf  = (__hip_bfloat16*)(ws + OFF_VBUF);
  __hip_bfloat16* yA    = (__hip_bfloat16*)(ws + OFF_YA);
  __hip_bfloat16* wcat  = (__hip_bfloat16*)(ws + OFF_WCAT);
  __hip_bfloat16* wdtbc = (__hip_bfloat16*)(ws + OFF_WDTBC);
  __hip_bfloat16* w2T   = (__hip_bfloat16*)(ws + OFF_W2T);
  float* Btf = (float*)(ws + OFF_BT);
  float* Ctf = (float*)(ws + OFF_CT);
  float* P   = (float*)(ws + OFF_P);
  float* H   = (float*)(ws + OFF_H);

  // prep (z 0..4) + layernorm (z 5..12) in one dispatch
  k_prep_ln<<<dim3(32, 32, 13), 256, 0, stream>>>(w1_w, v1_w, W_dt, w2_w, W_B, W_C,
                                                  wcat, wdtbc, w2T, x, ln_g, ln_b, xnorm);

  k_gemm_xv<<<dim3(BL / 128, 2048 / 256), 256, 0, stream>>>(
      xnorm, wcat, (void*)x1, (void*)vbuf, w1_b, v1_b);

  k_conv_silu<<<(BL * DD / 8) / 256, 256, 0, stream>>>(x1, conv_w, xconv);

  k_gemm_dbc<<<dim3(BL / 128, 1280 / 256), 256, 0, stream>>>(
      xconv, wdtbc, (void*)dtb, (void*)Btf, (void*)Ctf, b_dt);

  k_scan1<<<dim3(DD / 256, NC, BB), 256, 0, stream>>>(dtb, xconv, Btf, A_log, P, H);
  k_scan2<<<(BB * DD * NN) / 256, 256, 0, stream>>>(P, H);
  k_scan3<<<dim3(DD / 256, NC, BB), 256, 0, stream>>>(dtb, xconv, Btf, Ctf, A_log, H, D_skip,
                                                      vbuf, yA);

  k_gemm_out<<<dim3(BL / 128, 1024 / 256), 256, 0, stream>>>(yA, w2T, d_out, w2_b);
}

// Round 5
// 371.180 us; speedup vs baseline: 1.5000x; 1.3452x over previous
//
#include <hip/hip_runtime.h>
#include <hip/hip_bf16.h>

// Problem constants
#define BB 4
#define LL 2048
#define DD 1024
#define NN 16
#define BL (BB * LL)   // 8192 rows
#define NC 32          // scan chunks per sequence
#define LC 64          // chunk length (NC*LC == LL)
#define MB 1048576

typedef float f32x4 __attribute__((ext_vector_type(4)));
typedef __bf16 bf16x8 __attribute__((ext_vector_type(8)));

typedef __attribute__((address_space(1))) unsigned int as1_u32;
typedef __attribute__((address_space(3))) unsigned int as3_u32;

__device__ __forceinline__ void gl_lds16(const void* g, void* l) {
  // async global->LDS, 16B per lane, dest = uniform base + lane*16
  __builtin_amdgcn_global_load_lds((as1_u32*)g, (as3_u32*)l, 16, 0, 0);
}

__device__ __forceinline__ float fast_sigmoid(float x) {
  return 1.f / (1.f + __expf(-x));
}

// ---------------- fused weight prep + layernorm (one dispatch) ----------------
// z<4 : transpose+cvt 1024x1024 f32 (K x N) -> N x K bf16 slabs
// z==4: pack W_B/W_C into wdtbc rows 1024..1055; zero rows 1056..1151
// z>=5: layernorm row (z-5)*1024 + by*32 + bx  (8 z-slices = 8192 rows)
__global__ __launch_bounds__(256) void k_prep_ln(const float* __restrict__ w1,
                                                 const float* __restrict__ v1,
                                                 const float* __restrict__ wdt,
                                                 const float* __restrict__ w2,
                                                 const float* __restrict__ WB,
                                                 const float* __restrict__ WC,
                                                 __hip_bfloat16* __restrict__ wcat,
                                                 __hip_bfloat16* __restrict__ wdtbc,
                                                 __hip_bfloat16* __restrict__ w2T,
                                                 const float* __restrict__ x,
                                                 const float* __restrict__ ln_g,
                                                 const float* __restrict__ ln_b,
                                                 __hip_bfloat16* __restrict__ xnorm) {
  const int z = blockIdx.z;
  __shared__ float tile[32][33];
  __shared__ float red[8];
  if (z < 4) {
    const float* src = (z == 0) ? w1 : (z == 1) ? v1 : (z == 2) ? wdt : w2;
    __hip_bfloat16* dst = (z == 0) ? wcat
                        : (z == 1) ? (wcat + (size_t)1024 * DD)
                        : (z == 2) ? wdtbc : w2T;
    const int kt = blockIdx.x * 32, nt = blockIdx.y * 32;
    const int tx = threadIdx.x & 31, ty = threadIdx.x >> 5;  // ty 0..7
#pragma unroll
    for (int j = 0; j < 32; j += 8)
      tile[ty + j][tx] = src[(size_t)(kt + ty + j) * DD + nt + tx];
    __syncthreads();
#pragma unroll
    for (int j = 0; j < 32; j += 8)
      dst[(size_t)(nt + ty + j) * DD + kt + tx] = __float2bfloat16(tile[tx][ty + j]);
  } else if (z == 4) {
    const int id = blockIdx.y * 32 + blockIdx.x;  // 0..1023
    if (id < 128) {
      const int idx = id * 256 + threadIdx.x;  // 0..32767
      const int k = idx & 1023, n = idx >> 10;  // n in 0..31
      const float v = (n < 16) ? WB[(size_t)k * 16 + n] : WC[(size_t)k * 16 + (n - 16)];
      wdtbc[(size_t)(1024 + n) * DD + k] = __float2bfloat16(v);
    } else if (id < 512) {
      const int idx = (id - 128) * 256 + threadIdx.x;  // 0..98303 = 96*1024
      wdtbc[(size_t)1056 * DD + idx] = __float2bfloat16(0.f);
    }
  } else {
    const int row = (z - 5) * 1024 + blockIdx.y * 32 + blockIdx.x;
    const int tid = threadIdx.x;
    const f32x4 xv = *(const f32x4*)(x + (size_t)row * DD + tid * 4);
    float s = xv[0] + xv[1] + xv[2] + xv[3];
    float sq = xv[0] * xv[0] + xv[1] * xv[1] + xv[2] * xv[2] + xv[3] * xv[3];
#pragma unroll
    for (int o = 32; o > 0; o >>= 1) {
      s += __shfl_down(s, o);
      sq += __shfl_down(sq, o);
    }
    const int wave = tid >> 6, lane = tid & 63;
    if (lane == 0) { red[wave] = s; red[4 + wave] = sq; }
    __syncthreads();
    s = red[0] + red[1] + red[2] + red[3];
    sq = red[4] + red[5] + red[6] + red[7];
    const float mean = s * (1.f / DD);
    const float var = sq * (1.f / DD) - mean * mean;
    const float rs = rsqrtf(var + 1e-5f);
    const f32x4 gv = *(const f32x4*)(ln_g + tid * 4);
    const f32x4 bv = *(const f32x4*)(ln_b + tid * 4);
    union { ushort4 u; __hip_bfloat16 h[4]; } cv;
#pragma unroll
    for (int j = 0; j < 4; ++j)
      cv.h[j] = __float2bfloat16((xv[j] - mean) * rs * gv[j] + bv[j]);
    *reinterpret_cast<ushort4*>(&xnorm[(size_t)row * DD + tid * 4]) = cv.u;
  }
}

// ---------------- bf16 MFMA GEMM, 128x128 tile, BK=64, 4 waves, XOR-swizzled LDS ----------------
// Same register/occupancy point as the proven R1 config (acc[4][4], 3 waves/SIMD),
// but HALF the barrier count (16 iters x 2 barriers for the same 512 wave-MFMAs)
// and bank-conflict-free LDS reads: staging fetches global 16B-chunk
// (lane&7)^(row&7) so LDS chunk p of row r holds global chunk p^(r&7); fragment
// reads XOR-compensate -> reads spread over all 32 banks (2-way residual, free).
// A: M x 1024 bf16 row-major. W: N x 1024 bf16 row-major (pre-transposed).
// EPI 1: o0=x1(bf16,+bias0), o1=v(bf16, silu(+bias1))           [N=2048]
// EPI 2: o0=dt(bf16, softplus(+bias0)), o1=Bt(f32), o2=Ct(f32)  [N=1152]
// EPI 3: o0=out(f32, +bias0)                                    [N=1024]
template <int EPI>
__device__ __forceinline__ void gemm_body(const __hip_bfloat16* __restrict__ Ag,
                                          const __hip_bfloat16* __restrict__ Wg,
                                          void* __restrict__ o0, void* __restrict__ o1,
                                          void* __restrict__ o2,
                                          const float* __restrict__ bias0,
                                          const float* __restrict__ bias1) {
  __shared__ unsigned short As[128 * 64];  // 16 KB, row = 128B (8 chunks of 16B)
  __shared__ unsigned short Bs[128 * 64];  // 16 KB
  const int tid = threadIdx.x;
  const int wave = tid >> 6, lane = tid & 63;
  const int quad = lane >> 4, l16 = lane & 15;
  const int wm = wave & 1, wn = wave >> 1;

  // staging: per wave 32 rows of A + 32 rows of B per iter, 4 issues of 8 rows each
  const int srow = lane >> 3;                    // row within 8-row issue group
  const int schunk = (lane & 7) ^ srow;          // swizzled source chunk
  const char* gA = (const char*)Ag +
      (size_t)(blockIdx.x * 128 + wave * 32 + srow) * 2048 + schunk * 16;
  const char* gB = (const char*)Wg +
      (size_t)(blockIdx.y * 128 + wave * 32 + srow) * 2048 + schunk * 16;
  char* lA = (char*)As + wave * 32 * 128;
  char* lB = (char*)Bs + wave * 32 * 128;

  f32x4 acc[4][4] = {};

  for (int kt = 0; kt < 16; ++kt) {
#pragma unroll
    for (int i = 0; i < 4; ++i) {
      gl_lds16(gA + i * 8 * 2048, lA + i * 1024);
      gl_lds16(gB + i * 8 * 2048, lB + i * 1024);
    }
    gA += 128;
    gB += 128;
    __syncthreads();  // drains vmcnt -> LDS tiles ready
    bf16x8 af[2][4], bfr[2][4];
#pragma unroll
    for (int h = 0; h < 2; ++h)
#pragma unroll
      for (int i = 0; i < 4; ++i) {
        const int ra = wm * 64 + i * 16 + l16;
        const int rb = wn * 64 + i * 16 + l16;
        af[h][i] = *(const bf16x8*)((const char*)As + ra * 128 +
                                    (((h * 4 + quad) ^ (ra & 7)) * 16));
        bfr[h][i] = *(const bf16x8*)((const char*)Bs + rb * 128 +
                                     (((h * 4 + quad) ^ (rb & 7)) * 16));
      }
#pragma unroll
    for (int h = 0; h < 2; ++h)
#pragma unroll
      for (int i = 0; i < 4; ++i)
#pragma unroll
        for (int j = 0; j < 4; ++j)
          acc[i][j] =
              __builtin_amdgcn_mfma_f32_16x16x32_bf16(af[h][i], bfr[h][j], acc[i][j], 0, 0, 0);
    __syncthreads();  // everyone done reading before next stage overwrites
  }

  // epilogue: C/D layout col = lane&15, row = quad*4 + reg  [verified m89/m91]
  const int em0 = blockIdx.x * 128 + wm * 64 + quad * 4;
  const int en0 = blockIdx.y * 128 + wn * 64 + l16;
#pragma unroll
  for (int i = 0; i < 4; ++i) {
#pragma unroll
    for (int r = 0; r < 4; ++r) {
      const int m = em0 + i * 16 + r;
#pragma unroll
      for (int j = 0; j < 4; ++j) {
        const int n = en0 + j * 16;
        const float val = acc[i][j][r];
        if constexpr (EPI == 1) {
          if (n < 1024) {
            ((__hip_bfloat16*)o0)[(size_t)m * DD + n] = __float2bfloat16(val + bias0[n]);
          } else {
            const float t = val + bias1[n - 1024];
            ((__hip_bfloat16*)o1)[(size_t)m * DD + (n - 1024)] =
                __float2bfloat16(t * fast_sigmoid(t));
          }
        } else if constexpr (EPI == 2) {
          if (n < 1024) {
            const float t = val + bias0[n];
            const float sp = (t > 15.f) ? t : __logf(1.f + __expf(t));
            ((__hip_bfloat16*)o0)[(size_t)m * DD + n] = __float2bfloat16(sp);
          } else if (n < 1040) {
            ((float*)o1)[(size_t)m * NN + (n - 1024)] = val;
          } else if (n < 1056) {
            ((float*)o2)[(size_t)m * NN + (n - 1040)] = val;
          }  // n >= 1056: padding, discard
        } else {
          ((float*)o0)[(size_t)m * DD + n] = val + bias0[n];
        }
      }
    }
  }
}

__global__ __launch_bounds__(256) void k_gemm_xv(const __hip_bfloat16* __restrict__ Ag,
                                                 const __hip_bfloat16* __restrict__ Wg,
                                                 void* o0, void* o1,
                                                 const float* __restrict__ b0,
                                                 const float* __restrict__ b1) {
  gemm_body<1>(Ag, Wg, o0, o1, nullptr, b0, b1);
}
__global__ __launch_bounds__(256) void k_gemm_dbc(const __hip_bfloat16* __restrict__ Ag,
                                                  const __hip_bfloat16* __restrict__ Wg,
                                                  void* o0, void* o1, void* o2,
                                                  const float* __restrict__ b0) {
  gemm_body<2>(Ag, Wg, o0, o1, o2, b0, nullptr);
}
__global__ __launch_bounds__(256) void k_gemm_out(const __hip_bfloat16* __restrict__ Ag,
                                                  const __hip_bfloat16* __restrict__ Wg,
                                                  void* o0, const float* __restrict__ b0) {
  gemm_body<3>(Ag, Wg, o0, nullptr, nullptr, b0, nullptr);
}

// ---------------- depthwise conv3 (pad 1) + SiLU, bf16 -> bf16, x8 vectorized ----------------
__global__ __launch_bounds__(256) void k_conv_silu(const __hip_bfloat16* __restrict__ x1,
                                                   const float* __restrict__ w,
                                                   __hip_bfloat16* __restrict__ out) {
  const size_t e = ((size_t)blockIdx.x * 256 + threadIdx.x) * 8;  // elem idx over BL*D
  const int d = (int)(e & 1023);
  const int l = (int)((e >> 10) & 2047);
  const bf16x8 zero = {};
  const bf16x8 xm = (l > 0) ? *(const bf16x8*)(x1 + e - DD) : zero;
  const bf16x8 x0 = *(const bf16x8*)(x1 + e);
  const bf16x8 xp = (l < LL - 1) ? *(const bf16x8*)(x1 + e + DD) : zero;
  bf16x8 o;
#pragma unroll
  for (int j = 0; j < 8; ++j) {
    const float w0 = w[(d + j) * 3 + 0], w1 = w[(d + j) * 3 + 1], w2 = w[(d + j) * 3 + 2];
    const float a = w0 * (float)xm[j] + w1 * (float)x0[j] + w2 * (float)xp[j];
    o[j] = (__bf16)(a * fast_sigmoid(a));
  }
  *(bf16x8*)(out + e) = o;
}

// ---------------- selective scan, chunked (3 passes) ----------------
// pass 1: per (b, chunk, d): local scan from h=0 -> h_end; P = exp(A * sum(dt))
__global__ __launch_bounds__(256) void k_scan1(const __hip_bfloat16* __restrict__ dt,
                                               const __hip_bfloat16* __restrict__ u,
                                               const float* __restrict__ Bt,
                                               const float* __restrict__ A_log,
                                               float* __restrict__ P,
                                               float* __restrict__ hend) {
  const int d = blockIdx.x * 256 + threadIdx.x;
  const int c = blockIdx.y, b = blockIdx.z;
  __shared__ float Bsh[LC * NN];  // 4KB
  ((f32x4*)Bsh)[threadIdx.x] = ((const f32x4*)(Bt + (size_t)(b * LL + c * LC) * NN))[threadIdx.x];
  float a[NN];
#pragma unroll
  for (int n = 0; n < NN; ++n) a[n] = -__expf(A_log[(size_t)d * NN + n]);
  __syncthreads();
  float h[NN] = {};
  float sdt = 0.f;
  size_t idx = (size_t)(b * LL + c * LC) * DD + d;
#pragma unroll 4
  for (int t = 0; t < LC; ++t, idx += DD) {
    const float dtv = __bfloat162float(dt[idx]);
    const float uv = __bfloat162float(u[idx]);
    sdt += dtv;
    const float du = dtv * uv;
#pragma unroll
    for (int n = 0; n < NN; ++n)
      h[n] = __expf(dtv * a[n]) * h[n] + du * Bsh[t * NN + n];
  }
  const size_t o = ((size_t)((b * NC + c) * DD + d)) * NN;
#pragma unroll
  for (int n = 0; n < NN; ++n) {
    P[o + n] = __expf(sdt * a[n]);
    hend[o + n] = h[n];
  }
}

// pass 2: tiny inter-chunk scan per (b,d,n); converts hend -> hstart in place
__global__ __launch_bounds__(256) void k_scan2(const float* __restrict__ P, float* __restrict__ h) {
  const int gidx = blockIdx.x * 256 + threadIdx.x;  // BB*DD*NN = 65536
  const int n = gidx & 15, d = (gidx >> 4) & 1023, b = gidx >> 14;
  float hs = 0.f;
  size_t off = ((size_t)b * NC * DD + d) * NN + n;
  const size_t stride = (size_t)DD * NN;
  for (int c = 0; c < NC; ++c, off += stride) {
    const float he = h[off];
    const float p = P[off];
    h[off] = hs;  // now h_start for chunk c
    hs = p * hs + he;
  }
}

// pass 3: re-scan with correct h_start, compute y, fuse D_skip and *v, emit bf16 A for GEMM3
__global__ __launch_bounds__(256) void k_scan3(const __hip_bfloat16* __restrict__ dt,
                                               const __hip_bfloat16* __restrict__ u,
                                               const float* __restrict__ Bt,
                                               const float* __restrict__ Ct,
                                               const float* __restrict__ A_log,
                                               const float* __restrict__ hstart,
                                               const float* __restrict__ Dskip,
                                               const __hip_bfloat16* __restrict__ v,
                                               __hip_bfloat16* __restrict__ yA) {
  const int d = blockIdx.x * 256 + threadIdx.x;
  const int c = blockIdx.y, b = blockIdx.z;
  __shared__ float Bsh[LC * NN];
  __shared__ float Csh[LC * NN];
  ((f32x4*)Bsh)[threadIdx.x] = ((const f32x4*)(Bt + (size_t)(b * LL + c * LC) * NN))[threadIdx.x];
  ((f32x4*)Csh)[threadIdx.x] = ((const f32x4*)(Ct + (size_t)(b * LL + c * LC) * NN))[threadIdx.x];
  float a[NN];
#pragma unroll
  for (int n = 0; n < NN; ++n) a[n] = -__expf(A_log[(size_t)d * NN + n]);
  const float dsk = Dskip[d];
  float h[NN];
  const size_t o = ((size_t)((b * NC + c) * DD + d)) * NN;
#pragma unroll
  for (int n = 0; n < NN; ++n) h[n] = hstart[o + n];
  __syncthreads();
  size_t idx = (size_t)(b * LL + c * LC) * DD + d;
#pragma unroll 2
  for (int t = 0; t < LC; ++t, idx += DD) {
    const float dtv = __bfloat162float(dt[idx]);
    const float uv = __bfloat162float(u[idx]);
    const float du = dtv * uv;
    float y = 0.f;
#pragma unroll
    for (int n = 0; n < NN; ++n) {
      h[n] = __expf(dtv * a[n]) * h[n] + du * Bsh[t * NN + n];
      y += h[n] * Csh[t * NN + n];
    }
    const float xssm = y + uv * dsk;
    const float vv = __bfloat162float(v[idx]);
    yA[idx] = __float2bfloat16(xssm * vv);
  }
}

// ---------------- host launcher ----------------
extern "C" void kernel_launch(void* const* d_in, const int* in_sizes, int n_in,
                              void* d_out, int out_size, void* d_ws, size_t ws_size,
                              hipStream_t stream) {
  const float* x      = (const float*)d_in[0];
  const float* ln_g   = (const float*)d_in[1];
  const float* ln_b   = (const float*)d_in[2];
  const float* w1_w   = (const float*)d_in[3];
  const float* w1_b   = (const float*)d_in[4];
  const float* v1_w   = (const float*)d_in[5];
  const float* v1_b   = (const float*)d_in[6];
  const float* w2_w   = (const float*)d_in[7];
  const float* w2_b   = (const float*)d_in[8];
  const float* conv_w = (const float*)d_in[9];
  const float* A_log  = (const float*)d_in[10];
  const float* D_skip = (const float*)d_in[11];
  const float* W_dt   = (const float*)d_in[12];
  const float* b_dt   = (const float*)d_in[13];
  const float* W_B    = (const float*)d_in[14];
  const float* W_C    = (const float*)d_in[15];

  char* ws = (char*)d_ws;
  // byte offsets (lifetime-overlapped), total ~89.3 MB
  const size_t OFF_SLOTA = 0;                    // xnorm -> later xconv (16 MB)
  const size_t OFF_SLOTB = (size_t)16 * MB;      // x1 -> later dt       (16 MB)
  const size_t OFF_VBUF  = (size_t)32 * MB;      // v bf16               (16 MB)
  const size_t OFF_YA    = (size_t)48 * MB;      // (x_ssm*v) bf16       (16 MB)
  const size_t OFF_WCAT  = (size_t)64 * MB;      // [w1;v1]^T 2048x1024   (4 MB)
  const size_t OFF_WDTBC = (size_t)68 * MB;      // [W_dt;B;C;pad]^T 1152x1024 (2.25 MB)
  const size_t OFF_W2T   = OFF_WDTBC + 2359296;  // w2^T 1024x1024        (2 MB)
  const size_t OFF_BT    = OFF_W2T + 2097152;    // Bt f32 8192x16      (0.5 MB)
  const size_t OFF_CT    = OFF_BT + 524288;      // Ct f32 8192x16      (0.5 MB)
  const size_t OFF_P     = OFF_CT + 524288;      // chunk decay products  (8 MB)
  const size_t OFF_H     = OFF_P + 8388608;      // chunk h_end->h_start  (8 MB)

  __hip_bfloat16* xnorm = (__hip_bfloat16*)(ws + OFF_SLOTA);
  __hip_bfloat16* xconv = (__hip_bfloat16*)(ws + OFF_SLOTA);
  __hip_bfloat16* x1    = (__hip_bfloat16*)(ws + OFF_SLOTB);
  __hip_bfloat16* dtb   = (__hip_bfloat16*)(ws + OFF_SLOTB);
  __hip_bfloat16* vbuf  = (__hip_bfloat16*)(ws + OFF_VBUF);
  __hip_bfloat16* yA    = (__hip_bfloat16*)(ws + OFF_YA);
  __hip_bfloat16* wcat  = (__hip_bfloat16*)(ws + OFF_WCAT);
  __hip_bfloat16* wdtbc = (__hip_bfloat16*)(ws + OFF_WDTBC);
  __hip_bfloat16* w2T   = (__hip_bfloat16*)(ws + OFF_W2T);
  float* Btf = (float*)(ws + OFF_BT);
  float* Ctf = (float*)(ws + OFF_CT);
  float* P   = (float*)(ws + OFF_P);
  float* H   = (float*)(ws + OFF_H);

  // prep (z 0..4) + layernorm (z 5..12) in one dispatch
  k_prep_ln<<<dim3(32, 32, 13), 256, 0, stream>>>(w1_w, v1_w, W_dt, w2_w, W_B, W_C,
                                                  wcat, wdtbc, w2T, x, ln_g, ln_b, xnorm);

  k_gemm_xv<<<dim3(BL / 128, 2048 / 128), 256, 0, stream>>>(
      xnorm, wcat, (void*)x1, (void*)vbuf, w1_b, v1_b);

  k_conv_silu<<<(BL * DD / 8) / 256, 256, 0, stream>>>(x1, conv_w, xconv);

  k_gemm_dbc<<<dim3(BL / 128, 1152 / 128), 256, 0, stream>>>(
      xconv, wdtbc, (void*)dtb, (void*)Btf, (void*)Ctf, b_dt);

  k_scan1<<<dim3(DD / 256, NC, BB), 256, 0, stream>>>(dtb, xconv, Btf, A_log, P, H);
  k_scan2<<<(BB * DD * NN) / 256, 256, 0, stream>>>(P, H);
  k_scan3<<<dim3(DD / 256, NC, BB), 256, 0, stream>>>(dtb, xconv, Btf, Ctf, A_log, H, D_skip,
                                                      vbuf, yA);

  k_gemm_out<<<dim3(BL / 128, 1024 / 128), 256, 0, stream>>>(yA, w2T, d_out, w2_b);
}

// Round 6
// 340.676 us; speedup vs baseline: 1.6343x; 1.0895x over previous
//
#include <hip/hip_runtime.h>
#include <hip/hip_bf16.h>

// Problem constants
#define BB 4
#define LL 2048
#define DD 1024
#define NN 16
#define BL (BB * LL)   // 8192 rows
#define NC 64          // scan chunks per sequence
#define LC 32          // chunk length (NC*LC == LL)
#define MB 1048576

typedef float f32x4 __attribute__((ext_vector_type(4)));
typedef __bf16 bf16x8 __attribute__((ext_vector_type(8)));

typedef __attribute__((address_space(1))) unsigned int as1_u32;
typedef __attribute__((address_space(3))) unsigned int as3_u32;

__device__ __forceinline__ void gl_lds16(const void* g, void* l) {
  // async global->LDS, 16B per lane, dest = uniform base + lane*16
  __builtin_amdgcn_global_load_lds((as1_u32*)g, (as3_u32*)l, 16, 0, 0);
}

__device__ __forceinline__ float fast_sigmoid(float x) {
  return 1.f / (1.f + __expf(-x));
}

// ---------------- fused weight prep + layernorm (one dispatch) ----------------
// z<4 : transpose+cvt 1024x1024 f32 (K x N) -> N x K bf16 slabs
// z==4: pack W_B/W_C into wdtbc rows 1024..1055; zero rows 1056..1151
// z>=5: layernorm row (z-5)*1024 + by*32 + bx  (8 z-slices = 8192 rows)
__global__ __launch_bounds__(256) void k_prep_ln(const float* __restrict__ w1,
                                                 const float* __restrict__ v1,
                                                 const float* __restrict__ wdt,
                                                 const float* __restrict__ w2,
                                                 const float* __restrict__ WB,
                                                 const float* __restrict__ WC,
                                                 __hip_bfloat16* __restrict__ wcat,
                                                 __hip_bfloat16* __restrict__ wdtbc,
                                                 __hip_bfloat16* __restrict__ w2T,
                                                 const float* __restrict__ x,
                                                 const float* __restrict__ ln_g,
                                                 const float* __restrict__ ln_b,
                                                 __hip_bfloat16* __restrict__ xnorm) {
  const int z = blockIdx.z;
  __shared__ float tile[32][33];
  __shared__ float red[8];
  if (z < 4) {
    const float* src = (z == 0) ? w1 : (z == 1) ? v1 : (z == 2) ? wdt : w2;
    __hip_bfloat16* dst = (z == 0) ? wcat
                        : (z == 1) ? (wcat + (size_t)1024 * DD)
                        : (z == 2) ? wdtbc : w2T;
    const int kt = blockIdx.x * 32, nt = blockIdx.y * 32;
    const int tx = threadIdx.x & 31, ty = threadIdx.x >> 5;  // ty 0..7
#pragma unroll
    for (int j = 0; j < 32; j += 8)
      tile[ty + j][tx] = src[(size_t)(kt + ty + j) * DD + nt + tx];
    __syncthreads();
#pragma unroll
    for (int j = 0; j < 32; j += 8)
      dst[(size_t)(nt + ty + j) * DD + kt + tx] = __float2bfloat16(tile[tx][ty + j]);
  } else if (z == 4) {
    const int id = blockIdx.y * 32 + blockIdx.x;  // 0..1023
    if (id < 128) {
      const int idx = id * 256 + threadIdx.x;  // 0..32767
      const int k = idx & 1023, n = idx >> 10;  // n in 0..31
      const float v = (n < 16) ? WB[(size_t)k * 16 + n] : WC[(size_t)k * 16 + (n - 16)];
      wdtbc[(size_t)(1024 + n) * DD + k] = __float2bfloat16(v);
    } else if (id < 512) {
      const int idx = (id - 128) * 256 + threadIdx.x;  // 0..98303 = 96*1024
      wdtbc[(size_t)1056 * DD + idx] = __float2bfloat16(0.f);
    }
  } else {
    const int row = (z - 5) * 1024 + blockIdx.y * 32 + blockIdx.x;
    const int tid = threadIdx.x;
    const f32x4 xv = *(const f32x4*)(x + (size_t)row * DD + tid * 4);
    float s = xv[0] + xv[1] + xv[2] + xv[3];
    float sq = xv[0] * xv[0] + xv[1] * xv[1] + xv[2] * xv[2] + xv[3] * xv[3];
#pragma unroll
    for (int o = 32; o > 0; o >>= 1) {
      s += __shfl_down(s, o);
      sq += __shfl_down(sq, o);
    }
    const int wave = tid >> 6, lane = tid & 63;
    if (lane == 0) { red[wave] = s; red[4 + wave] = sq; }
    __syncthreads();
    s = red[0] + red[1] + red[2] + red[3];
    sq = red[4] + red[5] + red[6] + red[7];
    const float mean = s * (1.f / DD);
    const float var = sq * (1.f / DD) - mean * mean;
    const float rs = rsqrtf(var + 1e-5f);
    const f32x4 gv = *(const f32x4*)(ln_g + tid * 4);
    const f32x4 bv = *(const f32x4*)(ln_b + tid * 4);
    union { ushort4 u; __hip_bfloat16 h[4]; } cv;
#pragma unroll
    for (int j = 0; j < 4; ++j)
      cv.h[j] = __float2bfloat16((xv[j] - mean) * rs * gv[j] + bv[j]);
    *reinterpret_cast<ushort4*>(&xnorm[(size_t)row * DD + tid * 4]) = cv.u;
  }
}

// ---------------- bf16 MFMA GEMM, 128x128 tile, BK=64, 4 waves, XOR-swizzled LDS ----------------
// R5-verified config: acc[4][4] (3 waves/SIMD), 16 K-iters x 2 barriers,
// bank-conflict-free swizzled LDS (SQ_LDS_BANK_CONFLICT == 0). FROZEN.
// A: M x 1024 bf16 row-major. W: N x 1024 bf16 row-major (pre-transposed).
// EPI 1: o0=x1(bf16,+bias0), o1=v(bf16, silu(+bias1))           [N=2048]
// EPI 2: o0=dt(bf16, softplus(+bias0)), o1=Bt(f32), o2=Ct(f32)  [N=1152]
// EPI 3: o0=out(f32, +bias0)                                    [N=1024]
template <int EPI>
__device__ __forceinline__ void gemm_body(const __hip_bfloat16* __restrict__ Ag,
                                          const __hip_bfloat16* __restrict__ Wg,
                                          void* __restrict__ o0, void* __restrict__ o1,
                                          void* __restrict__ o2,
                                          const float* __restrict__ bias0,
                                          const float* __restrict__ bias1) {
  __shared__ unsigned short As[128 * 64];  // 16 KB, row = 128B (8 chunks of 16B)
  __shared__ unsigned short Bs[128 * 64];  // 16 KB
  const int tid = threadIdx.x;
  const int wave = tid >> 6, lane = tid & 63;
  const int quad = lane >> 4, l16 = lane & 15;
  const int wm = wave & 1, wn = wave >> 1;

  // staging: per wave 32 rows of A + 32 rows of B per iter, 4 issues of 8 rows each
  const int srow = lane >> 3;                    // row within 8-row issue group
  const int schunk = (lane & 7) ^ srow;          // swizzled source chunk
  const char* gA = (const char*)Ag +
      (size_t)(blockIdx.x * 128 + wave * 32 + srow) * 2048 + schunk * 16;
  const char* gB = (const char*)Wg +
      (size_t)(blockIdx.y * 128 + wave * 32 + srow) * 2048 + schunk * 16;
  char* lA = (char*)As + wave * 32 * 128;
  char* lB = (char*)Bs + wave * 32 * 128;

  f32x4 acc[4][4] = {};

  for (int kt = 0; kt < 16; ++kt) {
#pragma unroll
    for (int i = 0; i < 4; ++i) {
      gl_lds16(gA + i * 8 * 2048, lA + i * 1024);
      gl_lds16(gB + i * 8 * 2048, lB + i * 1024);
    }
    gA += 128;
    gB += 128;
    __syncthreads();  // drains vmcnt -> LDS tiles ready
    bf16x8 af[2][4], bfr[2][4];
#pragma unroll
    for (int h = 0; h < 2; ++h)
#pragma unroll
      for (int i = 0; i < 4; ++i) {
        const int ra = wm * 64 + i * 16 + l16;
        const int rb = wn * 64 + i * 16 + l16;
        af[h][i] = *(const bf16x8*)((const char*)As + ra * 128 +
                                    (((h * 4 + quad) ^ (ra & 7)) * 16));
        bfr[h][i] = *(const bf16x8*)((const char*)Bs + rb * 128 +
                                     (((h * 4 + quad) ^ (rb & 7)) * 16));
      }
#pragma unroll
    for (int h = 0; h < 2; ++h)
#pragma unroll
      for (int i = 0; i < 4; ++i)
#pragma unroll
        for (int j = 0; j < 4; ++j)
          acc[i][j] =
              __builtin_amdgcn_mfma_f32_16x16x32_bf16(af[h][i], bfr[h][j], acc[i][j], 0, 0, 0);
    __syncthreads();  // everyone done reading before next stage overwrites
  }

  // epilogue: C/D layout col = lane&15, row = quad*4 + reg  [verified m89/m91]
  const int em0 = blockIdx.x * 128 + wm * 64 + quad * 4;
  const int en0 = blockIdx.y * 128 + wn * 64 + l16;
#pragma unroll
  for (int i = 0; i < 4; ++i) {
#pragma unroll
    for (int r = 0; r < 4; ++r) {
      const int m = em0 + i * 16 + r;
#pragma unroll
      for (int j = 0; j < 4; ++j) {
        const int n = en0 + j * 16;
        const float val = acc[i][j][r];
        if constexpr (EPI == 1) {
          if (n < 1024) {
            ((__hip_bfloat16*)o0)[(size_t)m * DD + n] = __float2bfloat16(val + bias0[n]);
          } else {
            const float t = val + bias1[n - 1024];
            ((__hip_bfloat16*)o1)[(size_t)m * DD + (n - 1024)] =
                __float2bfloat16(t * fast_sigmoid(t));
          }
        } else if constexpr (EPI == 2) {
          if (n < 1024) {
            const float t = val + bias0[n];
            const float sp = (t > 15.f) ? t : __logf(1.f + __expf(t));
            ((__hip_bfloat16*)o0)[(size_t)m * DD + n] = __float2bfloat16(sp);
          } else if (n < 1040) {
            ((float*)o1)[(size_t)m * NN + (n - 1024)] = val;
          } else if (n < 1056) {
            ((float*)o2)[(size_t)m * NN + (n - 1040)] = val;
          }  // n >= 1056: padding, discard
        } else {
          ((float*)o0)[(size_t)m * DD + n] = val + bias0[n];
        }
      }
    }
  }
}

__global__ __launch_bounds__(256) void k_gemm_xv(const __hip_bfloat16* __restrict__ Ag,
                                                 const __hip_bfloat16* __restrict__ Wg,
                                                 void* o0, void* o1,
                                                 const float* __restrict__ b0,
                                                 const float* __restrict__ b1) {
  gemm_body<1>(Ag, Wg, o0, o1, nullptr, b0, b1);
}
__global__ __launch_bounds__(256) void k_gemm_dbc(const __hip_bfloat16* __restrict__ Ag,
                                                  const __hip_bfloat16* __restrict__ Wg,
                                                  void* o0, void* o1, void* o2,
                                                  const float* __restrict__ b0) {
  gemm_body<2>(Ag, Wg, o0, o1, o2, b0, nullptr);
}
__global__ __launch_bounds__(256) void k_gemm_out(const __hip_bfloat16* __restrict__ Ag,
                                                  const __hip_bfloat16* __restrict__ Wg,
                                                  void* o0, const float* __restrict__ b0) {
  gemm_body<3>(Ag, Wg, o0, nullptr, nullptr, b0, nullptr);
}

// ---------------- depthwise conv3 (pad 1) + SiLU, bf16 -> bf16, x8 vectorized ----------------
__global__ __launch_bounds__(256) void k_conv_silu(const __hip_bfloat16* __restrict__ x1,
                                                   const float* __restrict__ w,
                                                   __hip_bfloat16* __restrict__ out) {
  const size_t e = ((size_t)blockIdx.x * 256 + threadIdx.x) * 8;  // elem idx over BL*D
  const int d = (int)(e & 1023);
  const int l = (int)((e >> 10) & 2047);
  const bf16x8 zero = {};
  const bf16x8 xm = (l > 0) ? *(const bf16x8*)(x1 + e - DD) : zero;
  const bf16x8 x0 = *(const bf16x8*)(x1 + e);
  const bf16x8 xp = (l < LL - 1) ? *(const bf16x8*)(x1 + e + DD) : zero;
  bf16x8 o;
#pragma unroll
  for (int j = 0; j < 8; ++j) {
    const float w0 = w[(d + j) * 3 + 0], w1 = w[(d + j) * 3 + 1], w2 = w[(d + j) * 3 + 2];
    const float a = w0 * (float)xm[j] + w1 * (float)x0[j] + w2 * (float)xp[j];
    o[j] = (__bf16)(a * fast_sigmoid(a));
  }
  *(bf16x8*)(out + e) = o;
}

// ---------------- selective scan, chunked (3 passes) ----------------
// The provided A_log[d,n] = log(n+1) makes a[n] = -(n+1) = (n+1)*a[0]:
// exp(dt*a[n]) = exp(dt*a0)^(n+1) -> 1 transcendental + 15 muls (log-depth tree)
// instead of 16 transcendentals per step. Wave-uniform runtime check with the
// generic path as fallback, so the kernel stays correct for any A_log.

// pass 1: per (b, chunk, d): local scan from h=0 -> h_end; P = exp(A * sum(dt))
__global__ __launch_bounds__(256) void k_scan1(const __hip_bfloat16* __restrict__ dt,
                                               const __hip_bfloat16* __restrict__ u,
                                               const float* __restrict__ Bt,
                                               const float* __restrict__ A_log,
                                               float* __restrict__ P,
                                               float* __restrict__ hend) {
  const int d = blockIdx.x * 256 + threadIdx.x;
  const int c = blockIdx.y, b = blockIdx.z;
  __shared__ float Bsh[LC * NN];  // 2KB
  if (threadIdx.x < LC * NN / 4)
    ((f32x4*)Bsh)[threadIdx.x] =
        ((const f32x4*)(Bt + (size_t)(b * LL + c * LC) * NN))[threadIdx.x];
  float a[NN];
#pragma unroll
  for (int n = 0; n < NN; ++n) a[n] = -__expf(A_log[(size_t)d * NN + n]);
  const float a0 = a[0];
  bool pw = true;
#pragma unroll
  for (int n = 0; n < NN; ++n) pw &= (fabsf(a[n] - (n + 1) * a0) <= 1e-3f * (n + 1));
  __syncthreads();
  float h[NN] = {};
  float sdt = 0.f;
  size_t idx = (size_t)(b * LL + c * LC) * DD + d;
  if (pw) {
#pragma unroll 2
    for (int t = 0; t < LC; ++t, idx += DD) {
      const float dtv = __bfloat162float(dt[idx]);
      const float uv = __bfloat162float(u[idx]);
      sdt += dtv;
      const float du = dtv * uv;
      float w[NN];
      w[0] = __expf(dtv * a0);
#pragma unroll
      for (int n = 1; n < NN; ++n) w[n] = w[(n - 1) >> 1] * w[n >> 1];  // w[n]=eb^(n+1)
#pragma unroll
      for (int n = 0; n < NN; ++n) h[n] = w[n] * h[n] + du * Bsh[t * NN + n];
    }
  } else {
#pragma unroll 2
    for (int t = 0; t < LC; ++t, idx += DD) {
      const float dtv = __bfloat162float(dt[idx]);
      const float uv = __bfloat162float(u[idx]);
      sdt += dtv;
      const float du = dtv * uv;
#pragma unroll
      for (int n = 0; n < NN; ++n)
        h[n] = __expf(dtv * a[n]) * h[n] + du * Bsh[t * NN + n];
    }
  }
  const size_t o = ((size_t)((b * NC + c) * DD + d)) * NN;
  float p[NN];
  if (pw) {
    p[0] = __expf(sdt * a0);
#pragma unroll
    for (int n = 1; n < NN; ++n) p[n] = p[(n - 1) >> 1] * p[n >> 1];
  } else {
#pragma unroll
    for (int n = 0; n < NN; ++n) p[n] = __expf(sdt * a[n]);
  }
#pragma unroll
  for (int n = 0; n < NN; ++n) {
    P[o + n] = p[n];
    hend[o + n] = h[n];
  }
}

// pass 2: tiny inter-chunk scan per (b,d,n); converts hend -> hstart in place
__global__ __launch_bounds__(256) void k_scan2(const float* __restrict__ P, float* __restrict__ h) {
  const int gidx = blockIdx.x * 256 + threadIdx.x;  // BB*DD*NN = 65536
  const int n = gidx & 15, d = (gidx >> 4) & 1023, b = gidx >> 14;
  float hs = 0.f;
  size_t off = ((size_t)b * NC * DD + d) * NN + n;
  const size_t stride = (size_t)DD * NN;
  for (int c = 0; c < NC; ++c, off += stride) {
    const float he = h[off];
    const float p = P[off];
    h[off] = hs;  // now h_start for chunk c
    hs = p * hs + he;
  }
}

// pass 3: re-scan with correct h_start, compute y, fuse D_skip and *v, emit bf16 A for GEMM3
__global__ __launch_bounds__(256) void k_scan3(const __hip_bfloat16* __restrict__ dt,
                                               const __hip_bfloat16* __restrict__ u,
                                               const float* __restrict__ Bt,
                                               const float* __restrict__ Ct,
                                               const float* __restrict__ A_log,
                                               const float* __restrict__ hstart,
                                               const float* __restrict__ Dskip,
                                               const __hip_bfloat16* __restrict__ v,
                                               __hip_bfloat16* __restrict__ yA) {
  const int d = blockIdx.x * 256 + threadIdx.x;
  const int c = blockIdx.y, b = blockIdx.z;
  __shared__ float Bsh[LC * NN];  // 2KB
  __shared__ float Csh[LC * NN];  // 2KB
  if (threadIdx.x < 128)
    ((f32x4*)Bsh)[threadIdx.x] =
        ((const f32x4*)(Bt + (size_t)(b * LL + c * LC) * NN))[threadIdx.x];
  else
    ((f32x4*)Csh)[threadIdx.x - 128] =
        ((const f32x4*)(Ct + (size_t)(b * LL + c * LC) * NN))[threadIdx.x - 128];
  float a[NN];
#pragma unroll
  for (int n = 0; n < NN; ++n) a[n] = -__expf(A_log[(size_t)d * NN + n]);
  const float a0 = a[0];
  bool pw = true;
#pragma unroll
  for (int n = 0; n < NN; ++n) pw &= (fabsf(a[n] - (n + 1) * a0) <= 1e-3f * (n + 1));
  const float dsk = Dskip[d];
  float h[NN];
  const size_t o = ((size_t)((b * NC + c) * DD + d)) * NN;
#pragma unroll
  for (int n = 0; n < NN; ++n) h[n] = hstart[o + n];
  __syncthreads();
  size_t idx = (size_t)(b * LL + c * LC) * DD + d;
  if (pw) {
#pragma unroll 2
    for (int t = 0; t < LC; ++t, idx += DD) {
      const float dtv = __bfloat162float(dt[idx]);
      const float uv = __bfloat162float(u[idx]);
      const float du = dtv * uv;
      float w[NN];
      w[0] = __expf(dtv * a0);
#pragma unroll
      for (int n = 1; n < NN; ++n) w[n] = w[(n - 1) >> 1] * w[n >> 1];
      float y = 0.f;
#pragma unroll
      for (int n = 0; n < NN; ++n) {
        h[n] = w[n] * h[n] + du * Bsh[t * NN + n];
        y += h[n] * Csh[t * NN + n];
      }
      const float xssm = y + uv * dsk;
      const float vv = __bfloat162float(v[idx]);
      yA[idx] = __float2bfloat16(xssm * vv);
    }
  } else {
#pragma unroll 2
    for (int t = 0; t < LC; ++t, idx += DD) {
      const float dtv = __bfloat162float(dt[idx]);
      const float uv = __bfloat162float(u[idx]);
      const float du = dtv * uv;
      float y = 0.f;
#pragma unroll
      for (int n = 0; n < NN; ++n) {
        h[n] = __expf(dtv * a[n]) * h[n] + du * Bsh[t * NN + n];
        y += h[n] * Csh[t * NN + n];
      }
      const float xssm = y + uv * dsk;
      const float vv = __bfloat162float(v[idx]);
      yA[idx] = __float2bfloat16(xssm * vv);
    }
  }
}

// ---------------- host launcher ----------------
extern "C" void kernel_launch(void* const* d_in, const int* in_sizes, int n_in,
                              void* d_out, int out_size, void* d_ws, size_t ws_size,
                              hipStream_t stream) {
  const float* x      = (const float*)d_in[0];
  const float* ln_g   = (const float*)d_in[1];
  const float* ln_b   = (const float*)d_in[2];
  const float* w1_w   = (const float*)d_in[3];
  const float* w1_b   = (const float*)d_in[4];
  const float* v1_w   = (const float*)d_in[5];
  const float* v1_b   = (const float*)d_in[6];
  const float* w2_w   = (const float*)d_in[7];
  const float* w2_b   = (const float*)d_in[8];
  const float* conv_w = (const float*)d_in[9];
  const float* A_log  = (const float*)d_in[10];
  const float* D_skip = (const float*)d_in[11];
  const float* W_dt   = (const float*)d_in[12];
  const float* b_dt   = (const float*)d_in[13];
  const float* W_B    = (const float*)d_in[14];
  const float* W_C    = (const float*)d_in[15];

  char* ws = (char*)d_ws;
  // byte offsets (lifetime-overlapped), total ~89.3 MB.
  // P (16 MB, NC=64) aliases the yA region: P is written by scan1, read by scan2,
  // dead before scan3 writes yA there. H (16 MB) takes the old P+H span.
  const size_t OFF_SLOTA = 0;                    // xnorm -> later xconv (16 MB)
  const size_t OFF_SLOTB = (size_t)16 * MB;      // x1 -> later dt       (16 MB)
  const size_t OFF_VBUF  = (size_t)32 * MB;      // v bf16               (16 MB)
  const size_t OFF_YA    = (size_t)48 * MB;      // P f32 -> later (x_ssm*v) bf16 (16 MB)
  const size_t OFF_WCAT  = (size_t)64 * MB;      // [w1;v1]^T 2048x1024   (4 MB)
  const size_t OFF_WDTBC = (size_t)68 * MB;      // [W_dt;B;C;pad]^T 1152x1024 (2.25 MB)
  const size_t OFF_W2T   = OFF_WDTBC + 2359296;  // w2^T 1024x1024        (2 MB)
  const size_t OFF_BT    = OFF_W2T + 2097152;    // Bt f32 8192x16      (0.5 MB)
  const size_t OFF_CT    = OFF_BT + 524288;      // Ct f32 8192x16      (0.5 MB)
  const size_t OFF_H     = OFF_CT + 524288;      // chunk h_end->h_start (16 MB)

  __hip_bfloat16* xnorm = (__hip_bfloat16*)(ws + OFF_SLOTA);
  __hip_bfloat16* xconv = (__hip_bfloat16*)(ws + OFF_SLOTA);
  __hip_bfloat16* x1    = (__hip_bfloat16*)(ws + OFF_SLOTB);
  __hip_bfloat16* dtb   = (__hip_bfloat16*)(ws + OFF_SLOTB);
  __hip_bfloat16* vbuf  = (__hip_bfloat16*)(ws + OFF_VBUF);
  __hip_bfloat16* yA    = (__hip_bfloat16*)(ws + OFF_YA);
  float* P              = (float*)(ws + OFF_YA);   // alias (see above)
  __hip_bfloat16* wcat  = (__hip_bfloat16*)(ws + OFF_WCAT);
  __hip_bfloat16* wdtbc = (__hip_bfloat16*)(ws + OFF_WDTBC);
  __hip_bfloat16* w2T   = (__hip_bfloat16*)(ws + OFF_W2T);
  float* Btf = (float*)(ws + OFF_BT);
  float* Ctf = (float*)(ws + OFF_CT);
  float* H   = (float*)(ws + OFF_H);

  // prep (z 0..4) + layernorm (z 5..12) in one dispatch
  k_prep_ln<<<dim3(32, 32, 13), 256, 0, stream>>>(w1_w, v1_w, W_dt, w2_w, W_B, W_C,
                                                  wcat, wdtbc, w2T, x, ln_g, ln_b, xnorm);

  k_gemm_xv<<<dim3(BL / 128, 2048 / 128), 256, 0, stream>>>(
      xnorm, wcat, (void*)x1, (void*)vbuf, w1_b, v1_b);

  k_conv_silu<<<(BL * DD / 8) / 256, 256, 0, stream>>>(x1, conv_w, xconv);

  k_gemm_dbc<<<dim3(BL / 128, 1152 / 128), 256, 0, stream>>>(
      xconv, wdtbc, (void*)dtb, (void*)Btf, (void*)Ctf, b_dt);

  k_scan1<<<dim3(DD / 256, NC, BB), 256, 0, stream>>>(dtb, xconv, Btf, A_log, P, H);
  k_scan2<<<(BB * DD * NN) / 256, 256, 0, stream>>>(P, H);
  k_scan3<<<dim3(DD / 256, NC, BB), 256, 0, stream>>>(dtb, xconv, Btf, Ctf, A_log, H, D_skip,
                                                      vbuf, yA);

  k_gemm_out<<<dim3(BL / 128, 1024 / 128), 256, 0, stream>>>(yA, w2T, d_out, w2_b);
}

// Round 7
// 322.612 us; speedup vs baseline: 1.7258x; 1.0560x over previous
//
#include <hip/hip_runtime.h>
#include <hip/hip_bf16.h>

// Problem constants
#define BB 4
#define LL 2048
#define DD 1024
#define NN 16
#define BL (BB * LL)   // 8192 rows
#define NC 64          // scan chunks per sequence
#define LC 32          // chunk length (NC*LC == LL)
#define MB 1048576

typedef float f32x4 __attribute__((ext_vector_type(4)));
typedef __bf16 bf16x8 __attribute__((ext_vector_type(8)));

typedef __attribute__((address_space(1))) unsigned int as1_u32;
typedef __attribute__((address_space(3))) unsigned int as3_u32;

__device__ __forceinline__ void gl_lds16(const void* g, void* l) {
  // async global->LDS, 16B per lane, dest = uniform base + lane*16
  __builtin_amdgcn_global_load_lds((as1_u32*)g, (as3_u32*)l, 16, 0, 0);
}

__device__ __forceinline__ float fast_sigmoid(float x) {
  return 1.f / (1.f + __expf(-x));
}

// ---------------- fused weight prep + layernorm (one dispatch) ----------------
// z<4 : transpose+cvt 1024x1024 f32 (K x N) -> N x K bf16 slabs
// z==4: pack W_B/W_C into wdtbc rows 1024..1055; zero rows 1056..1151
// z>=5: layernorm row (z-5)*1024 + by*32 + bx  (8 z-slices = 8192 rows)
__global__ __launch_bounds__(256) void k_prep_ln(const float* __restrict__ w1,
                                                 const float* __restrict__ v1,
                                                 const float* __restrict__ wdt,
                                                 const float* __restrict__ w2,
                                                 const float* __restrict__ WB,
                                                 const float* __restrict__ WC,
                                                 __hip_bfloat16* __restrict__ wcat,
                                                 __hip_bfloat16* __restrict__ wdtbc,
                                                 __hip_bfloat16* __restrict__ w2T,
                                                 const float* __restrict__ x,
                                                 const float* __restrict__ ln_g,
                                                 const float* __restrict__ ln_b,
                                                 __hip_bfloat16* __restrict__ xnorm) {
  const int z = blockIdx.z;
  __shared__ float tile[32][33];
  __shared__ float red[8];
  if (z < 4) {
    const float* src = (z == 0) ? w1 : (z == 1) ? v1 : (z == 2) ? wdt : w2;
    __hip_bfloat16* dst = (z == 0) ? wcat
                        : (z == 1) ? (wcat + (size_t)1024 * DD)
                        : (z == 2) ? wdtbc : w2T;
    const int kt = blockIdx.x * 32, nt = blockIdx.y * 32;
    const int tx = threadIdx.x & 31, ty = threadIdx.x >> 5;  // ty 0..7
#pragma unroll
    for (int j = 0; j < 32; j += 8)
      tile[ty + j][tx] = src[(size_t)(kt + ty + j) * DD + nt + tx];
    __syncthreads();
#pragma unroll
    for (int j = 0; j < 32; j += 8)
      dst[(size_t)(nt + ty + j) * DD + kt + tx] = __float2bfloat16(tile[tx][ty + j]);
  } else if (z == 4) {
    const int id = blockIdx.y * 32 + blockIdx.x;  // 0..1023
    if (id < 128) {
      const int idx = id * 256 + threadIdx.x;  // 0..32767
      const int k = idx & 1023, n = idx >> 10;  // n in 0..31
      const float v = (n < 16) ? WB[(size_t)k * 16 + n] : WC[(size_t)k * 16 + (n - 16)];
      wdtbc[(size_t)(1024 + n) * DD + k] = __float2bfloat16(v);
    } else if (id < 512) {
      const int idx = (id - 128) * 256 + threadIdx.x;  // 0..98303 = 96*1024
      wdtbc[(size_t)1056 * DD + idx] = __float2bfloat16(0.f);
    }
  } else {
    const int row = (z - 5) * 1024 + blockIdx.y * 32 + blockIdx.x;
    const int tid = threadIdx.x;
    const f32x4 xv = *(const f32x4*)(x + (size_t)row * DD + tid * 4);
    float s = xv[0] + xv[1] + xv[2] + xv[3];
    float sq = xv[0] * xv[0] + xv[1] * xv[1] + xv[2] * xv[2] + xv[3] * xv[3];
#pragma unroll
    for (int o = 32; o > 0; o >>= 1) {
      s += __shfl_down(s, o);
      sq += __shfl_down(sq, o);
    }
    const int wave = tid >> 6, lane = tid & 63;
    if (lane == 0) { red[wave] = s; red[4 + wave] = sq; }
    __syncthreads();
    s = red[0] + red[1] + red[2] + red[3];
    sq = red[4] + red[5] + red[6] + red[7];
    const float mean = s * (1.f / DD);
    const float var = sq * (1.f / DD) - mean * mean;
    const float rs = rsqrtf(var + 1e-5f);
    const f32x4 gv = *(const f32x4*)(ln_g + tid * 4);
    const f32x4 bv = *(const f32x4*)(ln_b + tid * 4);
    union { ushort4 u; __hip_bfloat16 h[4]; } cv;
#pragma unroll
    for (int j = 0; j < 4; ++j)
      cv.h[j] = __float2bfloat16((xv[j] - mean) * rs * gv[j] + bv[j]);
    *reinterpret_cast<ushort4*>(&xnorm[(size_t)row * DD + tid * 4]) = cv.u;
  }
}

// ---------------- bf16 MFMA GEMM, 128x128 tile, BK=64, 4 waves, XOR-swizzled LDS ----------------
// R5-verified config: acc[4][4] (3 waves/SIMD), 16 K-iters x 2 barriers,
// bank-conflict-free swizzled LDS (SQ_LDS_BANK_CONFLICT == 0). FROZEN.
// A: M x 1024 bf16 row-major. W: N x 1024 bf16 row-major (pre-transposed).
// EPI 1: o0=x1(bf16,+bias0), o1=v(bf16, silu(+bias1))           [N=2048]
// EPI 2: o0=dt(bf16, softplus(+bias0)), o1=Bt(f32), o2=Ct(f32)  [N=1152]
// EPI 3: o0=out(f32, +bias0)                                    [N=1024]
template <int EPI>
__device__ __forceinline__ void gemm_body(const __hip_bfloat16* __restrict__ Ag,
                                          const __hip_bfloat16* __restrict__ Wg,
                                          void* __restrict__ o0, void* __restrict__ o1,
                                          void* __restrict__ o2,
                                          const float* __restrict__ bias0,
                                          const float* __restrict__ bias1) {
  __shared__ unsigned short As[128 * 64];  // 16 KB, row = 128B (8 chunks of 16B)
  __shared__ unsigned short Bs[128 * 64];  // 16 KB
  const int tid = threadIdx.x;
  const int wave = tid >> 6, lane = tid & 63;
  const int quad = lane >> 4, l16 = lane & 15;
  const int wm = wave & 1, wn = wave >> 1;

  // staging: per wave 32 rows of A + 32 rows of B per iter, 4 issues of 8 rows each
  const int srow = lane >> 3;                    // row within 8-row issue group
  const int schunk = (lane & 7) ^ srow;          // swizzled source chunk
  const char* gA = (const char*)Ag +
      (size_t)(blockIdx.x * 128 + wave * 32 + srow) * 2048 + schunk * 16;
  const char* gB = (const char*)Wg +
      (size_t)(blockIdx.y * 128 + wave * 32 + srow) * 2048 + schunk * 16;
  char* lA = (char*)As + wave * 32 * 128;
  char* lB = (char*)Bs + wave * 32 * 128;

  f32x4 acc[4][4] = {};

  for (int kt = 0; kt < 16; ++kt) {
#pragma unroll
    for (int i = 0; i < 4; ++i) {
      gl_lds16(gA + i * 8 * 2048, lA + i * 1024);
      gl_lds16(gB + i * 8 * 2048, lB + i * 1024);
    }
    gA += 128;
    gB += 128;
    __syncthreads();  // drains vmcnt -> LDS tiles ready
    bf16x8 af[2][4], bfr[2][4];
#pragma unroll
    for (int h = 0; h < 2; ++h)
#pragma unroll
      for (int i = 0; i < 4; ++i) {
        const int ra = wm * 64 + i * 16 + l16;
        const int rb = wn * 64 + i * 16 + l16;
        af[h][i] = *(const bf16x8*)((const char*)As + ra * 128 +
                                    (((h * 4 + quad) ^ (ra & 7)) * 16));
        bfr[h][i] = *(const bf16x8*)((const char*)Bs + rb * 128 +
                                     (((h * 4 + quad) ^ (rb & 7)) * 16));
      }
#pragma unroll
    for (int h = 0; h < 2; ++h)
#pragma unroll
      for (int i = 0; i < 4; ++i)
#pragma unroll
        for (int j = 0; j < 4; ++j)
          acc[i][j] =
              __builtin_amdgcn_mfma_f32_16x16x32_bf16(af[h][i], bfr[h][j], acc[i][j], 0, 0, 0);
    __syncthreads();  // everyone done reading before next stage overwrites
  }

  // epilogue: C/D layout col = lane&15, row = quad*4 + reg  [verified m89/m91]
  const int em0 = blockIdx.x * 128 + wm * 64 + quad * 4;
  const int en0 = blockIdx.y * 128 + wn * 64 + l16;
#pragma unroll
  for (int i = 0; i < 4; ++i) {
#pragma unroll
    for (int r = 0; r < 4; ++r) {
      const int m = em0 + i * 16 + r;
#pragma unroll
      for (int j = 0; j < 4; ++j) {
        const int n = en0 + j * 16;
        const float val = acc[i][j][r];
        if constexpr (EPI == 1) {
          if (n < 1024) {
            ((__hip_bfloat16*)o0)[(size_t)m * DD + n] = __float2bfloat16(val + bias0[n]);
          } else {
            const float t = val + bias1[n - 1024];
            ((__hip_bfloat16*)o1)[(size_t)m * DD + (n - 1024)] =
                __float2bfloat16(t * fast_sigmoid(t));
          }
        } else if constexpr (EPI == 2) {
          if (n < 1024) {
            const float t = val + bias0[n];
            const float sp = (t > 15.f) ? t : __logf(1.f + __expf(t));
            ((__hip_bfloat16*)o0)[(size_t)m * DD + n] = __float2bfloat16(sp);
          } else if (n < 1040) {
            ((float*)o1)[(size_t)m * NN + (n - 1024)] = val;
          } else if (n < 1056) {
            ((float*)o2)[(size_t)m * NN + (n - 1040)] = val;
          }  // n >= 1056: padding, discard
        } else {
          ((float*)o0)[(size_t)m * DD + n] = val + bias0[n];
        }
      }
    }
  }
}

__global__ __launch_bounds__(256) void k_gemm_xv(const __hip_bfloat16* __restrict__ Ag,
                                                 const __hip_bfloat16* __restrict__ Wg,
                                                 void* o0, void* o1,
                                                 const float* __restrict__ b0,
                                                 const float* __restrict__ b1) {
  gemm_body<1>(Ag, Wg, o0, o1, nullptr, b0, b1);
}
__global__ __launch_bounds__(256) void k_gemm_dbc(const __hip_bfloat16* __restrict__ Ag,
                                                  const __hip_bfloat16* __restrict__ Wg,
                                                  void* o0, void* o1, void* o2,
                                                  const float* __restrict__ b0) {
  gemm_body<2>(Ag, Wg, o0, o1, o2, b0, nullptr);
}
__global__ __launch_bounds__(256) void k_gemm_out(const __hip_bfloat16* __restrict__ Ag,
                                                  const __hip_bfloat16* __restrict__ Wg,
                                                  void* o0, const float* __restrict__ b0) {
  gemm_body<3>(Ag, Wg, o0, nullptr, nullptr, b0, nullptr);
}

// ---------------- depthwise conv3 (pad 1) + SiLU, bf16 -> bf16, x8 vectorized ----------------
// weights loaded as 6 x f32x4 (d multiple of 8 -> w + d*3 is 16B aligned)
__global__ __launch_bounds__(256) void k_conv_silu(const __hip_bfloat16* __restrict__ x1,
                                                   const float* __restrict__ w,
                                                   __hip_bfloat16* __restrict__ out) {
  const size_t e = ((size_t)blockIdx.x * 256 + threadIdx.x) * 8;  // elem idx over BL*D
  const int d = (int)(e & 1023);
  const int l = (int)((e >> 10) & 2047);
  const bf16x8 zero = {};
  const bf16x8 xm = (l > 0) ? *(const bf16x8*)(x1 + e - DD) : zero;
  const bf16x8 x0 = *(const bf16x8*)(x1 + e);
  const bf16x8 xp = (l < LL - 1) ? *(const bf16x8*)(x1 + e + DD) : zero;
  union { f32x4 v4[6]; float f[24]; } W;
  const f32x4* wp = (const f32x4*)(w + d * 3);
#pragma unroll
  for (int q = 0; q < 6; ++q) W.v4[q] = wp[q];
  bf16x8 o;
#pragma unroll
  for (int j = 0; j < 8; ++j) {
    const float a =
        W.f[j * 3 + 0] * (float)xm[j] + W.f[j * 3 + 1] * (float)x0[j] + W.f[j * 3 + 2] * (float)xp[j];
    o[j] = (__bf16)(a * fast_sigmoid(a));
  }
  *(bf16x8*)(out + e) = o;
}

// ---------------- selective scan, chunked (3 passes) ----------------
// The provided A_log[d,n] = log(n+1) makes a[n] = (n+1)*a[0]:
// exp(dt*a[n]) = exp(dt*a0)^(n+1) -> 1 transcendental + 15 muls (log-depth tree).
// Wave-uniform runtime check with generic fallback keeps it correct for any A_log.
// Chunk decay products are NOT materialized: scan1 stores sum(dt) (1 float per
// (b,c,d)) and scan2 recomputes p = exp(sdt*a[n]) exactly (general formula).

// pass 1: per (b, chunk, d): local scan from h=0 -> h_end; sdt = sum(dt)
__global__ __launch_bounds__(256) void k_scan1(const __hip_bfloat16* __restrict__ dt,
                                               const __hip_bfloat16* __restrict__ u,
                                               const float* __restrict__ Bt,
                                               const float* __restrict__ A_log,
                                               float* __restrict__ SD,
                                               float* __restrict__ hend) {
  const int d = blockIdx.x * 256 + threadIdx.x;
  const int c = blockIdx.y, b = blockIdx.z;
  __shared__ float Bsh[LC * NN];  // 2KB
  if (threadIdx.x < LC * NN / 4)
    ((f32x4*)Bsh)[threadIdx.x] =
        ((const f32x4*)(Bt + (size_t)(b * LL + c * LC) * NN))[threadIdx.x];
  float a[NN];
#pragma unroll
  for (int n = 0; n < NN; ++n) a[n] = -__expf(A_log[(size_t)d * NN + n]);
  const float a0 = a[0];
  bool pw = true;
#pragma unroll
  for (int n = 0; n < NN; ++n) pw &= (fabsf(a[n] - (n + 1) * a0) <= 1e-3f * (n + 1));
  __syncthreads();
  float h[NN] = {};
  float sdt = 0.f;
  size_t idx = (size_t)(b * LL + c * LC) * DD + d;
  if (pw) {
#pragma unroll 2
    for (int t = 0; t < LC; ++t, idx += DD) {
      const float dtv = __bfloat162float(dt[idx]);
      const float uv = __bfloat162float(u[idx]);
      sdt += dtv;
      const float du = dtv * uv;
      float w[NN];
      w[0] = __expf(dtv * a0);
#pragma unroll
      for (int n = 1; n < NN; ++n) w[n] = w[(n - 1) >> 1] * w[n >> 1];  // w[n]=eb^(n+1)
#pragma unroll
      for (int n = 0; n < NN; ++n) h[n] = w[n] * h[n] + du * Bsh[t * NN + n];
    }
  } else {
#pragma unroll 2
    for (int t = 0; t < LC; ++t, idx += DD) {
      const float dtv = __bfloat162float(dt[idx]);
      const float uv = __bfloat162float(u[idx]);
      sdt += dtv;
      const float du = dtv * uv;
#pragma unroll
      for (int n = 0; n < NN; ++n)
        h[n] = __expf(dtv * a[n]) * h[n] + du * Bsh[t * NN + n];
    }
  }
  const size_t o = ((size_t)((b * NC + c) * DD + d)) * NN;
  SD[(size_t)(b * NC + c) * DD + d] = sdt;
#pragma unroll
  for (int n = 0; n < NN; ++n) hend[o + n] = h[n];
}

// pass 2: tiny inter-chunk scan per (b,d,n); converts hend -> hstart in place.
// p = exp(sdt*a[n]) recomputed from the 1-float-per-chunk sdt (exact).
__global__ __launch_bounds__(256) void k_scan2(const float* __restrict__ SD,
                                               const float* __restrict__ A_log,
                                               float* __restrict__ h) {
  const int gidx = blockIdx.x * 256 + threadIdx.x;  // BB*DD*NN = 65536
  const int n = gidx & 15, d = (gidx >> 4) & 1023, b = gidx >> 14;
  const float an = -__expf(A_log[(size_t)d * NN + n]);
  float hs = 0.f;
  size_t off = ((size_t)b * NC * DD + d) * NN + n;
  size_t soff = (size_t)b * NC * DD + d;
  const size_t stride = (size_t)DD * NN;
  for (int c = 0; c < NC; ++c, off += stride, soff += DD) {
    const float he = h[off];
    const float p = __expf(SD[soff] * an);
    h[off] = hs;  // now h_start for chunk c
    hs = p * hs + he;
  }
}

// pass 3: re-scan with correct h_start, compute y, fuse D_skip and *v, emit bf16 A for GEMM3
__global__ __launch_bounds__(256) void k_scan3(const __hip_bfloat16* __restrict__ dt,
                                               const __hip_bfloat16* __restrict__ u,
                                               const float* __restrict__ Bt,
                                               const float* __restrict__ Ct,
                                               const float* __restrict__ A_log,
                                               const float* __restrict__ hstart,
                                               const float* __restrict__ Dskip,
                                               const __hip_bfloat16* __restrict__ v,
                                               __hip_bfloat16* __restrict__ yA) {
  const int d = blockIdx.x * 256 + threadIdx.x;
  const int c = blockIdx.y, b = blockIdx.z;
  __shared__ float Bsh[LC * NN];  // 2KB
  __shared__ float Csh[LC * NN];  // 2KB
  if (threadIdx.x < 128)
    ((f32x4*)Bsh)[threadIdx.x] =
        ((const f32x4*)(Bt + (size_t)(b * LL + c * LC) * NN))[threadIdx.x];
  else
    ((f32x4*)Csh)[threadIdx.x - 128] =
        ((const f32x4*)(Ct + (size_t)(b * LL + c * LC) * NN))[threadIdx.x - 128];
  float a[NN];
#pragma unroll
  for (int n = 0; n < NN; ++n) a[n] = -__expf(A_log[(size_t)d * NN + n]);
  const float a0 = a[0];
  bool pw = true;
#pragma unroll
  for (int n = 0; n < NN; ++n) pw &= (fabsf(a[n] - (n + 1) * a0) <= 1e-3f * (n + 1));
  const float dsk = Dskip[d];
  float h[NN];
  const size_t o = ((size_t)((b * NC + c) * DD + d)) * NN;
#pragma unroll
  for (int n = 0; n < NN; ++n) h[n] = hstart[o + n];
  __syncthreads();
  size_t idx = (size_t)(b * LL + c * LC) * DD + d;
  if (pw) {
#pragma unroll 2
    for (int t = 0; t < LC; ++t, idx += DD) {
      const float dtv = __bfloat162float(dt[idx]);
      const float uv = __bfloat162float(u[idx]);
      const float du = dtv * uv;
      float w[NN];
      w[0] = __expf(dtv * a0);
#pragma unroll
      for (int n = 1; n < NN; ++n) w[n] = w[(n - 1) >> 1] * w[n >> 1];
      float y = 0.f;
#pragma unroll
      for (int n = 0; n < NN; ++n) {
        h[n] = w[n] * h[n] + du * Bsh[t * NN + n];
        y += h[n] * Csh[t * NN + n];
      }
      const float xssm = y + uv * dsk;
      const float vv = __bfloat162float(v[idx]);
      yA[idx] = __float2bfloat16(xssm * vv);
    }
  } else {
#pragma unroll 2
    for (int t = 0; t < LC; ++t, idx += DD) {
      const float dtv = __bfloat162float(dt[idx]);
      const float uv = __bfloat162float(u[idx]);
      const float du = dtv * uv;
      float y = 0.f;
#pragma unroll
      for (int n = 0; n < NN; ++n) {
        h[n] = __expf(dtv * a[n]) * h[n] + du * Bsh[t * NN + n];
        y += h[n] * Csh[t * NN + n];
      }
      const float xssm = y + uv * dsk;
      const float vv = __bfloat162float(v[idx]);
      yA[idx] = __float2bfloat16(xssm * vv);
    }
  }
}

// ---------------- host launcher ----------------
extern "C" void kernel_launch(void* const* d_in, const int* in_sizes, int n_in,
                              void* d_out, int out_size, void* d_ws, size_t ws_size,
                              hipStream_t stream) {
  const float* x      = (const float*)d_in[0];
  const float* ln_g   = (const float*)d_in[1];
  const float* ln_b   = (const float*)d_in[2];
  const float* w1_w   = (const float*)d_in[3];
  const float* w1_b   = (const float*)d_in[4];
  const float* v1_w   = (const float*)d_in[5];
  const float* v1_b   = (const float*)d_in[6];
  const float* w2_w   = (const float*)d_in[7];
  const float* w2_b   = (const float*)d_in[8];
  const float* conv_w = (const float*)d_in[9];
  const float* A_log  = (const float*)d_in[10];
  const float* D_skip = (const float*)d_in[11];
  const float* W_dt   = (const float*)d_in[12];
  const float* b_dt   = (const float*)d_in[13];
  const float* W_B    = (const float*)d_in[14];
  const float* W_C    = (const float*)d_in[15];

  char* ws = (char*)d_ws;
  // byte offsets (lifetime-overlapped), total ~90.3 MB
  const size_t OFF_SLOTA = 0;                    // xnorm -> later xconv (16 MB)
  const size_t OFF_SLOTB = (size_t)16 * MB;      // x1 -> later dt       (16 MB)
  const size_t OFF_VBUF  = (size_t)32 * MB;      // v bf16               (16 MB)
  const size_t OFF_YA    = (size_t)48 * MB;      // (x_ssm*v) bf16       (16 MB)
  const size_t OFF_WCAT  = (size_t)64 * MB;      // [w1;v1]^T 2048x1024   (4 MB)
  const size_t OFF_WDTBC = (size_t)68 * MB;      // [W_dt;B;C;pad]^T 1152x1024 (2.25 MB)
  const size_t OFF_W2T   = OFF_WDTBC + 2359296;  // w2^T 1024x1024        (2 MB)
  const size_t OFF_BT    = OFF_W2T + 2097152;    // Bt f32 8192x16      (0.5 MB)
  const size_t OFF_CT    = OFF_BT + 524288;      // Ct f32 8192x16      (0.5 MB)
  const size_t OFF_SD    = OFF_CT + 524288;      // sdt f32 b,c,d         (1 MB)
  const size_t OFF_H     = OFF_SD + 1048576;     // chunk h_end->h_start (16 MB)

  __hip_bfloat16* xnorm = (__hip_bfloat16*)(ws + OFF_SLOTA);
  __hip_bfloat16* xconv = (__hip_bfloat16*)(ws + OFF_SLOTA);
  __hip_bfloat16* x1    = (__hip_bfloat16*)(ws + OFF_SLOTB);
  __hip_bfloat16* dtb   = (__hip_bfloat16*)(ws + OFF_SLOTB);
  __hip_bfloat16* vbuf  = (__hip_bfloat16*)(ws + OFF_VBUF);
  __hip_bfloat16* yA    = (__hip_bfloat16*)(ws + OFF_YA);
  __hip_bfloat16* wcat  = (__hip_bfloat16*)(ws + OFF_WCAT);
  __hip_bfloat16* wdtbc = (__hip_bfloat16*)(ws + OFF_WDTBC);
  __hip_bfloat16* w2T   = (__hip_bfloat16*)(ws + OFF_W2T);
  float* Btf = (float*)(ws + OFF_BT);
  float* Ctf = (float*)(ws + OFF_CT);
  float* SD  = (float*)(ws + OFF_SD);
  float* H   = (float*)(ws + OFF_H);

  // prep (z 0..4) + layernorm (z 5..12) in one dispatch
  k_prep_ln<<<dim3(32, 32, 13), 256, 0, stream>>>(w1_w, v1_w, W_dt, w2_w, W_B, W_C,
                                                  wcat, wdtbc, w2T, x, ln_g, ln_b, xnorm);

  k_gemm_xv<<<dim3(BL / 128, 2048 / 128), 256, 0, stream>>>(
      xnorm, wcat, (void*)x1, (void*)vbuf, w1_b, v1_b);

  k_conv_silu<<<(BL * DD / 8) / 256, 256, 0, stream>>>(x1, conv_w, xconv);

  k_gemm_dbc<<<dim3(BL / 128, 1152 / 128), 256, 0, stream>>>(
      xconv, wdtbc, (void*)dtb, (void*)Btf, (void*)Ctf, b_dt);

  k_scan1<<<dim3(DD / 256, NC, BB), 256, 0, stream>>>(dtb, xconv, Btf, A_log, SD, H);
  k_scan2<<<(BB * DD * NN) / 256, 256, 0, stream>>>(SD, A_log, H);
  k_scan3<<<dim3(DD / 256, NC, BB), 256, 0, stream>>>(dtb, xconv, Btf, Ctf, A_log, H, D_skip,
                                                      vbuf, yA);

  k_gemm_out<<<dim3(BL / 128, 1024 / 128), 256, 0, stream>>>(yA, w2T, d_out, w2_b);
}